// Round 13
// baseline (405.969 us; speedup 1.0000x reference)
//
#include <hip/hip_runtime.h>
#include <math.h>

#define TPB 256
#define NEG_SLOPE 0.2f
#define COS_EPS 1e-8f
#define NH 6
#define GSTRIDE 68   // LDS row stride (floats) for GEMM tiles
#define DCACHE 12    // rows cached in registers per node (slot 0 = self), branch-free
#define SALS 8       // sal row stride (floats), 32B-aligned

// ---------- helpers ----------
__device__ inline float wave_sum64(float v) {
  #pragma unroll
  for (int off = 32; off > 0; off >>= 1) v += __shfl_down(v, off);
  return __shfl(v, 0);
}
__device__ inline int wave_isum64(int v) {
  #pragma unroll
  for (int off = 32; off > 0; off >>= 1) v += __shfl_down(v, off);
  return v;   // valid in lane 0
}
__device__ inline unsigned short f2bf(float f) {
  unsigned u = __float_as_uint(f);
  unsigned r = (u + 0x7fffu + ((u >> 16) & 1u)) >> 16;   // RNE
  return (unsigned short)r;
}
__device__ inline float bf2f(unsigned short b) {
  return __uint_as_float(((unsigned)b) << 16);
}
__device__ inline unsigned packbf(float lo, float hi) {
  return (unsigned)f2bf(lo) | ((unsigned)f2bf(hi) << 16);
}
__device__ inline float bflo(unsigned u) { return __uint_as_float(u << 16); }
__device__ inline float bfhi(unsigned u) { return __uint_as_float(u & 0xffff0000u); }

#define GS_LOOP(i, total) \
  for (long i = (long)blockIdx.x * blockDim.x + threadIdx.x; i < (total); \
       i += (long)gridDim.x * blockDim.x)

// ---------- CSR build: ONLY the E real edges (self-loops handled analytically)
__global__ void k_cnt(const int* __restrict__ src, const int* __restrict__ dst,
                      int* __restrict__ gcnt, int* __restrict__ scnt, long E) {
  long half = (E + 1) >> 1;
  GS_LOOP(e2, half) {
    long e = 2 * e2;
    if (e + 1 < E) {
      int2 dv = *(const int2*)&dst[e];
      int2 sv = *(const int2*)&src[e];
      atomicAdd(&gcnt[dv.x], 1); atomicAdd(&gcnt[dv.y], 1);
      atomicAdd(&scnt[sv.x], 1); atomicAdd(&scnt[sv.y], 1);
    } else if (e < E) {
      atomicAdd(&gcnt[dst[e]], 1);
      atomicAdd(&scnt[src[e]], 1);
    }
  }
}

// phase A: per-tile sums + dinv = rsqrt(gcnt + 2)
__global__ __launch_bounds__(1024)
void k_scanA(const int* __restrict__ gcnt, const int* __restrict__ scnt,
             int* __restrict__ bsum, float* __restrict__ dinv, int n, int nb) {
  const int b = blockIdx.x;
  const bool isS = b >= nb;
  const int tb = isS ? b - nb : b;
  const int* cnt = isS ? scnt : gcnt;
  const int t = threadIdx.x;
  const int i0 = tb * 2048 + 2 * t;
  int v0 = (i0 < n) ? cnt[i0] : 0;
  int v1 = (i0 + 1 < n) ? cnt[i0 + 1] : 0;
  if (!isS) {
    if (i0 < n)     dinv[i0]     = rsqrtf((float)v0 + 2.0f);
    if (i0 + 1 < n) dinv[i0 + 1] = rsqrtf((float)v1 + 2.0f);
  }
  __shared__ int red[16];
  int x = v0 + v1;
  #pragma unroll
  for (int o = 32; o > 0; o >>= 1) x += __shfl_down(x, o);
  const int lane = t & 63, wv = t >> 6;
  if (lane == 0) red[wv] = x;
  __syncthreads();
  if (t < 64) {
    int w = (t < 16) ? red[t] : 0;
    #pragma unroll
    for (int o = 32; o > 0; o >>= 1) w += __shfl_down(w, o);
    if (t == 0) bsum[b] = w;
  }
}

// phase C: per-tile scan + writeback (computes own bsum prefix; nb <= 64)
__global__ __launch_bounds__(1024)
void k_scanC(const int* __restrict__ gcnt, int* __restrict__ goff, int* __restrict__ gcur,
             const int* __restrict__ scnt, int* __restrict__ soff, int* __restrict__ scur,
             const int* __restrict__ bsum, int n, int nb) {
  const int b = blockIdx.x;
  const bool isS = b >= nb;
  const int tb = isS ? b - nb : b;
  const int* cnt = isS ? scnt : gcnt;
  int* off = isS ? soff : goff;
  int* cur = isS ? scur : gcur;
  const int t = threadIdx.x;

  __shared__ int pfx_s;
  if (t < 64) {
    int v = (t < tb) ? bsum[(isS ? nb : 0) + t] : 0;
    v = wave_isum64(v);
    if (t == 0) pfx_s = v;
  }

  const int i0 = tb * 2048 + 2 * t;
  int v0 = (i0 < n) ? cnt[i0] : 0;
  int v1 = (i0 + 1 < n) ? cnt[i0 + 1] : 0;
  int s2 = v0 + v1;
  const int lane = t & 63, wv = t >> 6;
  int x = s2;
  #pragma unroll
  for (int d2 = 1; d2 < 64; d2 <<= 1) {
    int y = __shfl_up(x, d2);
    if (lane >= d2) x += y;
  }
  __shared__ int wsum[16];
  if (lane == 63) wsum[wv] = x;
  __syncthreads();
  if (t < 64) {
    int w = (t < 16) ? wsum[t] : 0;
    #pragma unroll
    for (int d2 = 1; d2 < 16; d2 <<= 1) {
      int y = __shfl_up(w, d2);
      if ((int)t >= d2) w += y;
    }
    if (t < 16) wsum[t] = w;
  }
  __syncthreads();
  int ex = x - s2 + (wv ? wsum[wv - 1] : 0) + pfx_s;
  if (i0 < n)     { cur[i0] = ex;          off[i0 + 1] = ex + v0; }
  if (i0 + 1 < n) { cur[i0 + 1] = ex + v0; off[i0 + 2] = ex + v0 + v1; }
  if (i0 == 0) off[0] = 0;
}

__global__ void k_scatter(const int* __restrict__ src, const int* __restrict__ dst,
                          int* __restrict__ gcur, int* __restrict__ gcsr,
                          int* __restrict__ scur, int* __restrict__ scsr, long E) {
  long half = (E + 1) >> 1;
  GS_LOOP(e2, half) {
    long e = 2 * e2;
    if (e + 1 < E) {
      int2 sv = *(const int2*)&src[e];
      int2 dv = *(const int2*)&dst[e];
      int p1 = atomicAdd(&gcur[dv.x], 1); gcsr[p1] = sv.x;
      int p2 = atomicAdd(&gcur[dv.y], 1); gcsr[p2] = sv.y;
      int p3 = atomicAdd(&scur[sv.x], 1); scsr[p3] = dv.x;
      int p4 = atomicAdd(&scur[sv.y], 1); scsr[p4] = dv.y;
    } else if (e < E) {
      int s = src[e], d = dst[e];
      int p1 = atomicAdd(&gcur[d], 1); gcsr[p1] = s;
      int p2 = atomicAdd(&scur[s], 1); scsr[p2] = d;
    }
  }
}

// ---------- GEMM: A[n][64] @ W[64][Mtot], 64x64 tile, 4x4 reg tile ----------
// MODE 1: bf16 out16, scaled by rowscale[row]  (hs = (x@Wg)*dinv).
// MODE 2: normalized bf16 rows (out16) + bsc[r] = A_row·W2 + b2.
template <int MODE>
__global__ __launch_bounds__(256)
void k_gemm64v3(const float* __restrict__ A, const float* __restrict__ W,
                float* __restrict__ out32, unsigned short* __restrict__ out16,
                const float* __restrict__ rowscale,
                const float* __restrict__ W2, const float* __restrict__ b2,
                float* __restrict__ bsc, int n, int Mtot) {
  __shared__ float At[64 * GSTRIDE];
  __shared__ float Wl[64 * GSTRIDE];
  const int t  = threadIdx.x;
  const int tx = t & 15;
  const int ty = t >> 4;
  const int col0 = blockIdx.y * 64;
  const long row0 = (long)blockIdx.x * 64;

  #pragma unroll
  for (int i = 0; i < 4; ++i) {
    int k = ty + 16 * i;
    float4 wv = *(const float4*)&W[(long)k * Mtot + col0 + 4 * tx];
    *(float4*)&Wl[k * GSTRIDE + 4 * tx] = wv;
  }
  #pragma unroll
  for (int i = 0; i < 4; ++i) {
    int r = ty + 16 * i;
    long gr = row0 + r; if (gr >= n) gr = n - 1;
    float4 av = *(const float4*)&A[gr * 64 + 4 * tx];
    At[(4 * tx + 0) * GSTRIDE + r] = av.x;
    At[(4 * tx + 1) * GSTRIDE + r] = av.y;
    At[(4 * tx + 2) * GSTRIDE + r] = av.z;
    At[(4 * tx + 3) * GSTRIDE + r] = av.w;
  }
  __syncthreads();

  const int c0 = 4 * tx;
  const int r0 = 4 * ty;
  float acc[4][4] = {};
  #pragma unroll
  for (int k = 0; k < 64; ++k) {
    float4 av = *(const float4*)&At[k * GSTRIDE + r0];
    float4 wv = *(const float4*)&Wl[k * GSTRIDE + c0];
    acc[0][0] = fmaf(av.x, wv.x, acc[0][0]); acc[0][1] = fmaf(av.x, wv.y, acc[0][1]);
    acc[0][2] = fmaf(av.x, wv.z, acc[0][2]); acc[0][3] = fmaf(av.x, wv.w, acc[0][3]);
    acc[1][0] = fmaf(av.y, wv.x, acc[1][0]); acc[1][1] = fmaf(av.y, wv.y, acc[1][1]);
    acc[1][2] = fmaf(av.y, wv.z, acc[1][2]); acc[1][3] = fmaf(av.y, wv.w, acc[1][3]);
    acc[2][0] = fmaf(av.z, wv.x, acc[2][0]); acc[2][1] = fmaf(av.z, wv.y, acc[2][1]);
    acc[2][2] = fmaf(av.z, wv.z, acc[2][2]); acc[2][3] = fmaf(av.z, wv.w, acc[2][3]);
    acc[3][0] = fmaf(av.w, wv.x, acc[3][0]); acc[3][1] = fmaf(av.w, wv.y, acc[3][1]);
    acc[3][2] = fmaf(av.w, wv.z, acc[3][2]); acc[3][3] = fmaf(av.w, wv.w, acc[3][3]);
  }

  if constexpr (MODE == 1) {
    #pragma unroll
    for (int i = 0; i < 4; ++i) {
      long gr = row0 + r0 + i;
      if (gr < n) {
        float sc = rowscale[gr];
        ushort4 v;
        v.x = f2bf(acc[i][0] * sc); v.y = f2bf(acc[i][1] * sc);
        v.z = f2bf(acc[i][2] * sc); v.w = f2bf(acc[i][3] * sc);
        *(ushort4*)&out16[gr * 64 + c0] = v;
      }
    }
  }
  if constexpr (MODE == 2) {
    float p[4], q[4];
    #pragma unroll
    for (int i = 0; i < 4; ++i) {
      q[i] = acc[i][0]*acc[i][0] + acc[i][1]*acc[i][1] +
             acc[i][2]*acc[i][2] + acc[i][3]*acc[i][3];
      p[i] = At[(c0+0) * GSTRIDE + r0 + i] * W2[c0+0] +
             At[(c0+1) * GSTRIDE + r0 + i] * W2[c0+1] +
             At[(c0+2) * GSTRIDE + r0 + i] * W2[c0+2] +
             At[(c0+3) * GSTRIDE + r0 + i] * W2[c0+3];
    }
    #pragma unroll
    for (int m = 1; m < 16; m <<= 1) {
      #pragma unroll
      for (int i = 0; i < 4; ++i) { p[i] += __shfl_xor(p[i], m); q[i] += __shfl_xor(q[i], m); }
    }
    float bb = b2[0];
    #pragma unroll
    for (int i = 0; i < 4; ++i) {
      long gr = row0 + r0 + i;
      if (gr < n) {
        float rn = 1.0f / fmaxf(sqrtf(q[i]), COS_EPS);
        ushort4 v;
        v.x = f2bf(acc[i][0] * rn); v.y = f2bf(acc[i][1] * rn);
        v.z = f2bf(acc[i][2] * rn); v.w = f2bf(acc[i][3] * rn);
        *(ushort4*)&out16[gr * 64 + c0] = v;
        if (tx == 0) bsc[gr] = p[i] + bb;
      }
    }
  }
}

// ---------- h2 GEMM: all 384 cols (6 heads) per block, packed channel-major out.
__global__ __launch_bounds__(256)
void k_gemm_h2(const float* __restrict__ A, const float* __restrict__ W,
               unsigned* __restrict__ h2p, const float* __restrict__ att,
               float* __restrict__ sal, int n) {
  __shared__ float At[64 * GSTRIDE];
  __shared__ float Wl[64 * GSTRIDE];
  const int t  = threadIdx.x;
  const int tx = t & 15;
  const int ty = t >> 4;
  const long row0 = (long)blockIdx.x * 64;
  const int c0 = 4 * tx;
  const int r0 = 4 * ty;

  #pragma unroll
  for (int i = 0; i < 4; ++i) {
    int r = ty + 16 * i;
    long gr = row0 + r; if (gr >= n) gr = n - 1;
    float4 av = *(const float4*)&A[gr * 64 + 4 * tx];
    At[(4 * tx + 0) * GSTRIDE + r] = av.x;
    At[(4 * tx + 1) * GSTRIDE + r] = av.y;
    At[(4 * tx + 2) * GSTRIDE + r] = av.z;
    At[(4 * tx + 3) * GSTRIDE + r] = av.w;
  }
  float4 wr[4];
  #pragma unroll
  for (int i = 0; i < 4; ++i)
    wr[i] = *(const float4*)&W[(long)(ty + 16 * i) * 384 + 4 * tx];

  float4 acc[6][4];
  #pragma unroll
  for (int h = 0; h < 6; ++h)
    #pragma unroll
    for (int i = 0; i < 4; ++i) acc[h][i] = make_float4(0.f, 0.f, 0.f, 0.f);

  #pragma unroll
  for (int head = 0; head < 6; ++head) {
    #pragma unroll
    for (int i = 0; i < 4; ++i)
      *(float4*)&Wl[(ty + 16 * i) * GSTRIDE + 4 * tx] = wr[i];
    __syncthreads();
    if (head < 5) {
      #pragma unroll
      for (int i = 0; i < 4; ++i)
        wr[i] = *(const float4*)&W[(long)(ty + 16 * i) * 384 + (head + 1) * 64 + 4 * tx];
    }
    #pragma unroll 16
    for (int k = 0; k < 64; ++k) {
      float4 av = *(const float4*)&At[k * GSTRIDE + r0];
      float4 wv = *(const float4*)&Wl[k * GSTRIDE + c0];
      acc[head][0].x = fmaf(av.x, wv.x, acc[head][0].x);
      acc[head][0].y = fmaf(av.x, wv.y, acc[head][0].y);
      acc[head][0].z = fmaf(av.x, wv.z, acc[head][0].z);
      acc[head][0].w = fmaf(av.x, wv.w, acc[head][0].w);
      acc[head][1].x = fmaf(av.y, wv.x, acc[head][1].x);
      acc[head][1].y = fmaf(av.y, wv.y, acc[head][1].y);
      acc[head][1].z = fmaf(av.y, wv.z, acc[head][1].z);
      acc[head][1].w = fmaf(av.y, wv.w, acc[head][1].w);
      acc[head][2].x = fmaf(av.z, wv.x, acc[head][2].x);
      acc[head][2].y = fmaf(av.z, wv.y, acc[head][2].y);
      acc[head][2].z = fmaf(av.z, wv.z, acc[head][2].z);
      acc[head][2].w = fmaf(av.z, wv.w, acc[head][2].w);
      acc[head][3].x = fmaf(av.w, wv.x, acc[head][3].x);
      acc[head][3].y = fmaf(av.w, wv.y, acc[head][3].y);
      acc[head][3].z = fmaf(av.w, wv.z, acc[head][3].z);
      acc[head][3].w = fmaf(av.w, wv.w, acc[head][3].w);
    }
    __syncthreads();
  }

  #pragma unroll
  for (int i = 0; i < 4; ++i) {
    long gr = row0 + r0 + i;
    if (gr < n) {
      uint4 u0, u1, u2;
      u0.x = packbf(acc[0][i].x, acc[1][i].x);
      u0.y = packbf(acc[2][i].x, acc[3][i].x);
      u0.z = packbf(acc[4][i].x, acc[5][i].x);
      u0.w = packbf(acc[0][i].y, acc[1][i].y);
      u1.x = packbf(acc[2][i].y, acc[3][i].y);
      u1.y = packbf(acc[4][i].y, acc[5][i].y);
      u1.z = packbf(acc[0][i].z, acc[1][i].z);
      u1.w = packbf(acc[2][i].z, acc[3][i].z);
      u2.x = packbf(acc[4][i].z, acc[5][i].z);
      u2.y = packbf(acc[0][i].w, acc[1][i].w);
      u2.z = packbf(acc[2][i].w, acc[3][i].w);
      u2.w = packbf(acc[4][i].w, acc[5][i].w);
      unsigned* dstp = &h2p[gr * 192 + c0 * 3];
      *(uint4*)(dstp + 0) = u0;
      *(uint4*)(dstp + 4) = u1;
      *(uint4*)(dstp + 8) = u2;
    }
  }
  #pragma unroll
  for (int head = 0; head < 6; ++head) {
    float a0 = att[head * 128 + c0 + 0], a1 = att[head * 128 + c0 + 1];
    float a2 = att[head * 128 + c0 + 2], a3 = att[head * 128 + c0 + 3];
    float p[4];
    #pragma unroll
    for (int i = 0; i < 4; ++i)
      p[i] = acc[head][i].x * a0 + acc[head][i].y * a1 +
             acc[head][i].z * a2 + acc[head][i].w * a3;
    #pragma unroll
    for (int m = 1; m < 16; m <<= 1) {
      #pragma unroll
      for (int i = 0; i < 4; ++i) p[i] += __shfl_xor(p[i], m);
    }
    if (tx == 0) {
      #pragma unroll
      for (int i = 0; i < 4; ++i) {
        long gr = row0 + r0 + i;
        if (gr < n) sal[gr * SALS + head] = p[i];
      }
    }
  }
}

// ---------- GCN aggregate via CSR (wave per node, paired lanes, bf16 rows) ----
__global__ __launch_bounds__(256)
void k_gcnb(const int* __restrict__ goff, const int* __restrict__ gcsr,
            const unsigned* __restrict__ hs32, const float* __restrict__ dinv,
            const float* __restrict__ bg, float* __restrict__ xpj, int n) {
  const int lane = threadIdx.x & 63;
  const int p = lane & 31;
  const int hf = lane >> 5;
  const int d = blockIdx.x * 4 + (threadIdx.x >> 6);
  if (d >= n) return;
  const int o0 = goff[d], o1 = goff[d + 1];
  float ax = 0.f, ay = 0.f;
  for (int j = o0 + hf; j < o1; j += 2) {
    long s = gcsr[j];
    unsigned u = hs32[s * 32 + p];
    ax += bflo(u); ay += bfhi(u);
  }
  ax += __shfl_xor(ax, 32);
  ay += __shfl_xor(ay, 32);
  if (hf == 0) {
    unsigned us = hs32[(long)d * 32 + p];
    float di = dinv[d];
    float2 bv = *(const float2*)&bg[2 * p];
    float2 r;
    r.x = bv.x + di * (ax + 2.0f * bflo(us));
    r.y = bv.y + di * (ay + 2.0f * bfhi(us));
    *(float2*)&xpj[(long)d * 64 + 2 * p] = r;
  }
}

// ---------- fused attention mega-kernel (wave per node; branch-free cache) ----
__global__ __launch_bounds__(256)
void k_mega(const int* __restrict__ soff, const int* __restrict__ scsr,
            const unsigned* __restrict__ h2p, const float* __restrict__ sal,
            const float* __restrict__ att, float* __restrict__ xm, int n) {
  const int lane = threadIdx.x & 63;
  const int d = blockIdx.x * 4 + (threadIdx.x >> 6);
  if (d >= n) return;
  const int o0 = soff[d], o1 = soff[d + 1];
  const int deg = o1 - o0;       // CSR edges (self excluded)
  const int td  = deg + 1;       // + self

  // ---- branch-free register cache: slot 0 = self, slots 1..11 clamped CSR ----
  // Slots beyond deg duplicate the last neighbor row (same line, L1-hot);
  // they are max-idempotent in hmax and weight-0 in the aggregate.
  unsigned ck0[DCACHE], ck1[DCACHE], ck2[DCACHE];
  {
    const int jmx = o1 - 1;
    #pragma unroll
    for (int k = 0; k < DCACHE; ++k) {
      long s;
      if (k == 0) s = d;
      else {
        int jcl = o0 + k - 1;
        if (jcl > jmx) jcl = jmx;
        s = (deg > 0) ? scsr[jcl] : d;   // deg==0: self (uniform select)
      }
      const unsigned* rp = &h2p[s * 192 + lane * 3];
      ck0[k] = rp[0]; ck1[k] = rp[1]; ck2[k] = rp[2];
    }
  }

  // ---- hmax over cache slots (dups harmless) + overflow rows ----
  float hm[NH];
  hm[0] = bflo(ck0[0]); hm[1] = bfhi(ck0[0]);
  hm[2] = bflo(ck1[0]); hm[3] = bfhi(ck1[0]);
  hm[4] = bflo(ck2[0]); hm[5] = bfhi(ck2[0]);
  #pragma unroll
  for (int k = 1; k < DCACHE; ++k) {
    hm[0] = fmaxf(hm[0], bflo(ck0[k])); hm[1] = fmaxf(hm[1], bfhi(ck0[k]));
    hm[2] = fmaxf(hm[2], bflo(ck1[k])); hm[3] = fmaxf(hm[3], bfhi(ck1[k]));
    hm[4] = fmaxf(hm[4], bflo(ck2[k])); hm[5] = fmaxf(hm[5], bfhi(ck2[k]));
  }
  for (int j = o0 + DCACHE - 1; j < o1; ++j) {
    long s = scsr[j];
    const unsigned* rp = &h2p[s * 192 + lane * 3];
    unsigned u0 = rp[0], u1 = rp[1], u2 = rp[2];
    hm[0] = fmaxf(hm[0], bflo(u0)); hm[1] = fmaxf(hm[1], bfhi(u0));
    hm[2] = fmaxf(hm[2], bflo(u1)); hm[3] = fmaxf(hm[3], bfhi(u1));
    hm[4] = fmaxf(hm[4], bflo(u2)); hm[5] = fmaxf(hm[5], bfhi(u2));
  }

  float dal[NH], K[NH];
  #pragma unroll
  for (int h = 0; h < NH; ++h) {
    dal[h] = wave_sum64(hm[h] * att[h * 128 + 64 + lane]);
    K[h] = fmaxf(dal[h], 0.f);
  }

  float acc[NH], den[NH];
  #pragma unroll
  for (int h = 0; h < NH; ++h) acc[h] = 0.f;

  if (td <= 64) {
    // ---- fast path: lane = edge (0 = self); branch-free ----
    const bool act = lane < td;
    float4 sA = make_float4(0, 0, 0, 0), sB = sA;
    if (act) {
      int sE = (lane == 0) ? d : scsr[o0 + lane - 1];
      const float4* sp = (const float4*)&sal[(long)sE * SALS];
      sA = sp[0]; sB = sp[1];
    }
    float svv[NH] = {sA.x, sA.y, sA.z, sA.w, sB.x, sB.y};
    float e6[NH];
    #pragma unroll
    for (int h = 0; h < NH; ++h) {
      float al = svv[h] + dal[h];
      al = (al >= 0.f) ? al : NEG_SLOPE * al;
      e6[h] = act ? expf(al - K[h]) : 0.f;
      den[h] = wave_sum64(e6[h]);
    }
    // aggregate cached slots (weights 0 beyond td)
    #pragma unroll
    for (int k = 0; k < DCACHE; ++k) {
      float w0 = __shfl(e6[0], k), w1 = __shfl(e6[1], k);
      float w2 = __shfl(e6[2], k), w3 = __shfl(e6[3], k);
      float w4 = __shfl(e6[4], k), w5 = __shfl(e6[5], k);
      acc[0] = fmaf(bflo(ck0[k]), w0, acc[0]);
      acc[1] = fmaf(bfhi(ck0[k]), w1, acc[1]);
      acc[2] = fmaf(bflo(ck1[k]), w2, acc[2]);
      acc[3] = fmaf(bfhi(ck1[k]), w3, acc[3]);
      acc[4] = fmaf(bflo(ck2[k]), w4, acc[4]);
      acc[5] = fmaf(bfhi(ck2[k]), w5, acc[5]);
    }
    // overflow edges (DCACHE-1 < j-index < deg): re-read rows
    for (int j = o0 + DCACHE - 1; j < o1; ++j) {
      int ii = j - o0 + 1;              // edge lane index (self = 0)
      long s = scsr[j];
      const unsigned* rp = &h2p[s * 192 + lane * 3];
      unsigned u0 = rp[0], u1 = rp[1], u2 = rp[2];
      float w0 = __shfl(e6[0], ii), w1 = __shfl(e6[1], ii);
      float w2 = __shfl(e6[2], ii), w3 = __shfl(e6[3], ii);
      float w4 = __shfl(e6[4], ii), w5 = __shfl(e6[5], ii);
      acc[0] = fmaf(bflo(u0), w0, acc[0]);
      acc[1] = fmaf(bfhi(u0), w1, acc[1]);
      acc[2] = fmaf(bflo(u1), w2, acc[2]);
      acc[3] = fmaf(bfhi(u1), w3, acc[3]);
      acc[4] = fmaf(bflo(u2), w4, acc[4]);
      acc[5] = fmaf(bfhi(u2), w5, acc[5]);
    }
  } else {
    // ---- slow path (td > 64): single pass, no max pre-pass ----
    {
      const float4* sp = (const float4*)&sal[(long)d * SALS];
      float4 sA = sp[0], sB = sp[1];
      float svv[NH] = {sA.x, sA.y, sA.z, sA.w, sB.x, sB.y};
      #pragma unroll
      for (int h = 0; h < NH; ++h) {
        float al = svv[h] + dal[h];
        al = (al >= 0.f) ? al : NEG_SLOPE * al;
        den[h] = expf(al - K[h]);
      }
    }
    acc[0] = bflo(ck0[0]) * den[0]; acc[1] = bfhi(ck0[0]) * den[1];
    acc[2] = bflo(ck1[0]) * den[2]; acc[3] = bfhi(ck1[0]) * den[3];
    acc[4] = bflo(ck2[0]) * den[4]; acc[5] = bfhi(ck2[0]) * den[5];
    for (int base = o0; base < o1; base += 64) {
      int cs = o1 - base; if (cs > 64) cs = 64;
      int j = base + lane;
      float e6[NH]; int s = 0;
      if (j < o1) {
        s = scsr[j];
        const float4* sp = (const float4*)&sal[(long)s * SALS];
        float4 sA = sp[0], sB = sp[1];
        float svv[NH] = {sA.x, sA.y, sA.z, sA.w, sB.x, sB.y};
        #pragma unroll
        for (int h = 0; h < NH; ++h) {
          float al = svv[h] + dal[h];
          al = (al >= 0.f) ? al : NEG_SLOPE * al;
          e6[h] = expf(al - K[h]);
        }
      } else {
        #pragma unroll
        for (int h = 0; h < NH; ++h) e6[h] = 0.f;
      }
      #pragma unroll
      for (int h = 0; h < NH; ++h) den[h] += wave_sum64(e6[h]);
      for (int jj = 0; jj < cs; ++jj) {
        int sj = __shfl(s, jj);
        const unsigned* rp = &h2p[(long)sj * 192 + lane * 3];
        unsigned u0 = rp[0], u1 = rp[1], u2 = rp[2];
        float w0 = __shfl(e6[0], jj), w1 = __shfl(e6[1], jj);
        float w2 = __shfl(e6[2], jj), w3 = __shfl(e6[3], jj);
        float w4 = __shfl(e6[4], jj), w5 = __shfl(e6[5], jj);
        acc[0] = fmaf(bflo(u0), w0, acc[0]);
        acc[1] = fmaf(bfhi(u0), w1, acc[1]);
        acc[2] = fmaf(bflo(u1), w2, acc[2]);
        acc[3] = fmaf(bfhi(u1), w3, acc[3]);
        acc[4] = fmaf(bflo(u2), w4, acc[4]);
        acc[5] = fmaf(bfhi(u2), w5, acc[5]);
      }
    }
  }

  float o = 0.f;
  #pragma unroll
  for (int h = 0; h < NH; ++h) o += acc[h] / den[h];
  xm[(long)d * 64 + lane] = o * (1.0f / NH);
}

// fitness[d] = sigmoid(bsc[d] * (1 + sum_CSR dot(an[s], an[d])))
__global__ __launch_bounds__(256)
void k_cosout(const int* __restrict__ soff, const int* __restrict__ scsr,
              const unsigned* __restrict__ an32, const float* __restrict__ bsc,
              float* __restrict__ out, int n) {
  const int lane = threadIdx.x & 63;
  const int p = lane & 31;
  const int hf = lane >> 5;
  const int d = blockIdx.x * 4 + (threadIdx.x >> 6);
  if (d >= n) return;
  const int o0 = soff[d], o1 = soff[d + 1];
  unsigned ud = an32[(long)d * 32 + p];
  float adx = bflo(ud), ady = bfhi(ud);
  float cl = 0.f;
  for (int j = o0 + hf; j < o1; j += 2) {
    long s = scsr[j];
    unsigned u = an32[s * 32 + p];
    cl += adx * bflo(u) + ady * bfhi(u);
  }
  float cs = wave_sum64(cl) + 1.0f;   // self-cosine == 1 exactly
  if (lane == 0) out[d] = 1.0f / (1.0f + expf(-bsc[d] * cs));
}

// ---------- launcher ----------
static inline unsigned gsblocks(long total) {
  long b = (total + TPB - 1) / TPB;
  if (b > 131072) b = 131072;
  return (unsigned)b;
}

extern "C" void kernel_launch(void* const* d_in, const int* in_sizes, int n_in,
                              void* d_out, int out_size, void* d_ws, size_t ws_size,
                              hipStream_t stream) {
  const float* x   = (const float*)d_in[0];
  const float* Wg  = (const float*)d_in[1];
  const float* bg  = (const float*)d_in[2];
  const float* Wt  = (const float*)d_in[3];
  const float* att = (const float*)d_in[4];
  const float* W1  = (const float*)d_in[5];
  const float* W2  = (const float*)d_in[6];
  const float* b2  = (const float*)d_in[7];
  const int* src   = (const int*)d_in[8];
  const int* dst   = (const int*)d_in[9];

  const long n   = in_sizes[0] / 64;   // 50000
  const long en  = in_sizes[8];        // E + N
  const long E   = en - n;             // real edges (ei), loops excluded
  const int  nb  = (int)((n + 2047) / 2048);

  char* base = (char*)d_ws;
  size_t off = 0;
  auto alloc = [&](size_t bytes) -> void* {
    void* p = base + off;
    off += (bytes + 255) & ~(size_t)255;
    return p;
  };
  int*   gcnt = (int*)alloc(n * 4);
  int*   scnt = (int*)alloc(n * 4);   // contiguous with gcnt (one memset)
  int*   goff = (int*)alloc((n + 1) * 4);
  int*   soff = (int*)alloc((n + 1) * 4);
  int*   gcur = (int*)alloc(n * 4);
  int*   scur = (int*)alloc(n * 4);
  int*   gcsr = (int*)alloc(E * 4);
  int*   scsr = (int*)alloc(E * 4);
  int*   bsum = (int*)alloc(2 * (size_t)nb * 4);
  float* dinv = (float*)alloc(n * 4);
  unsigned* hs32 = (unsigned*)alloc(n * 32 * 4);      // bf16 pairs of (x@Wg)*dinv
  float* xpj  = (float*)alloc(n * 64 * 4);            // later anorm (bf16)
  float* xmb  = (float*)alloc(n * 64 * 4);            // xm buffer
  unsigned* h2p = (unsigned*)alloc(n * 192 * 4);      // channel-major bf16 pairs
  float* sal  = (float*)alloc(n * SALS * 4);
  float* bsc  = (float*)alloc(n * 4);
  unsigned short* anorm = (unsigned short*)xpj;       // alias (xpj dead after h2)
  float* out  = (float*)d_out;

  const unsigned rowblk  = (unsigned)((n + 63) / 64);
  const unsigned nodeblk = (unsigned)((n + 3) / 4);

  // ---- CSR build (E edges only; self-loops analytic) + dinv ----
  hipMemsetAsync(gcnt, 0, (size_t)((char*)scnt - (char*)gcnt) + n * 4, stream);
  k_cnt<<<gsblocks((E + 1) / 2), TPB, 0, stream>>>(src, dst, gcnt, scnt, E);
  k_scanA<<<2 * nb, 1024, 0, stream>>>(gcnt, scnt, bsum, dinv, (int)n, nb);
  k_scanC<<<2 * nb, 1024, 0, stream>>>(gcnt, goff, gcur, scnt, soff, scur,
                                       bsum, (int)n, nb);
  k_scatter<<<gsblocks((E + 1) / 2), TPB, 0, stream>>>(src, dst, gcur, gcsr,
                                                       scur, scsr, E);

  // ---- hs = (x @ W_gcn) * dinv[row], bf16 ----
  { dim3 g(rowblk, 1);
    k_gemm64v3<1><<<g, 256, 0, stream>>>(x, Wg, nullptr, (unsigned short*)hs32,
                                         dinv, nullptr, nullptr, nullptr, (int)n, 64); }

  // ---- xpj = bg + dinv[d] * (2*hs[d] + sum_CSR hs[s]) ----
  k_gcnb<<<nodeblk, 256, 0, stream>>>(goff, gcsr, hs32, dinv, bg, xpj, (int)n);

  // ---- h2 = xpj @ weight (bf16 channel-major packed) + fused sal ----
  k_gemm_h2<<<rowblk, 256, 0, stream>>>(xpj, Wt, h2p, att, sal, (int)n);

  // ---- fused attention (self inline, branch-free cache) -> xm ----
  k_mega<<<nodeblk, 256, 0, stream>>>(soff, scsr, h2p, sal, att, xmb, (int)n);

  // ---- a = normalize(xm @ W1) (bf16, aliases xpj) + bsc ----
  { dim3 g(rowblk, 1);
    k_gemm64v3<2><<<g, 256, 0, stream>>>(xmb, W1, nullptr, anorm, nullptr,
                                         W2, b2, bsc, (int)n, 64); }

  // ---- cosine + sigmoid -> out (self-cos = 1 analytic) ----
  k_cosout<<<nodeblk, 256, 0, stream>>>(soff, scsr, (const unsigned*)anorm,
                                        bsc, out, (int)n);
}

// Round 14
// 354.395 us; speedup vs baseline: 1.1455x; 1.1455x over previous
//
#include <hip/hip_runtime.h>
#include <math.h>

#define TPB 256
#define NEG_SLOPE 0.2f
#define COS_EPS 1e-8f
#define NH 6
#define GSTRIDE 68   // LDS row stride (floats) for GEMM tiles
#define DCACHE 16    // rows cached in registers per node (slot 0 = self), guarded
#define SALS 8       // sal row stride (floats), 32B-aligned

// ---------- helpers ----------
__device__ inline float wave_sum64(float v) {
  #pragma unroll
  for (int off = 32; off > 0; off >>= 1) v += __shfl_down(v, off);
  return __shfl(v, 0);
}
__device__ inline int wave_isum64(int v) {
  #pragma unroll
  for (int off = 32; off > 0; off >>= 1) v += __shfl_down(v, off);
  return v;   // valid in lane 0
}
__device__ inline unsigned short f2bf(float f) {
  unsigned u = __float_as_uint(f);
  unsigned r = (u + 0x7fffu + ((u >> 16) & 1u)) >> 16;   // RNE
  return (unsigned short)r;
}
__device__ inline float bf2f(unsigned short b) {
  return __uint_as_float(((unsigned)b) << 16);
}
__device__ inline unsigned packbf(float lo, float hi) {
  return (unsigned)f2bf(lo) | ((unsigned)f2bf(hi) << 16);
}
__device__ inline float bflo(unsigned u) { return __uint_as_float(u << 16); }
__device__ inline float bfhi(unsigned u) { return __uint_as_float(u & 0xffff0000u); }

// float2 packed-math helpers (target: v_pk_*_f32 on CDNA4)
__device__ inline float2 pk2(float a, float b) { return make_float2(a, b); }
__device__ inline float2 up2(unsigned u) { return make_float2(bflo(u), bfhi(u)); }
__device__ inline float2 pk_add(float2 a, float2 b) { return make_float2(a.x + b.x, a.y + b.y); }
__device__ inline float2 pk_mul(float2 a, float2 b) { return make_float2(a.x * b.x, a.y * b.y); }
__device__ inline float2 pk_max(float2 a, float2 b) { return make_float2(fmaxf(a.x, b.x), fmaxf(a.y, b.y)); }
__device__ inline float2 pk_min(float2 a, float2 b) { return make_float2(fminf(a.x, b.x), fminf(a.y, b.y)); }
__device__ inline float2 pk_fma(float2 a, float2 b, float2 c) {
  return make_float2(fmaf(a.x, b.x, c.x), fmaf(a.y, b.y, c.y));
}
__device__ inline float2 wsum64_f2(float2 v) {
  #pragma unroll
  for (int off = 32; off > 0; off >>= 1) {
    v.x += __shfl_down(v.x, off);
    v.y += __shfl_down(v.y, off);
  }
  v.x = __shfl(v.x, 0); v.y = __shfl(v.y, 0);
  return v;
}

#define GS_LOOP(i, total) \
  for (long i = (long)blockIdx.x * blockDim.x + threadIdx.x; i < (total); \
       i += (long)gridDim.x * blockDim.x)

// ---------- CSR build: ONLY the E real edges (self-loops handled analytically)
__global__ void k_cnt(const int* __restrict__ src, const int* __restrict__ dst,
                      int* __restrict__ gcnt, int* __restrict__ scnt, long E) {
  GS_LOOP(e, E) {
    atomicAdd(&gcnt[dst[e]], 1);
    atomicAdd(&scnt[src[e]], 1);
  }
}

// phase A: per-tile sums + dinv = rsqrt(gcnt + 2)
__global__ __launch_bounds__(1024)
void k_scanA(const int* __restrict__ gcnt, const int* __restrict__ scnt,
             int* __restrict__ bsum, float* __restrict__ dinv, int n, int nb) {
  const int b = blockIdx.x;
  const bool isS = b >= nb;
  const int tb = isS ? b - nb : b;
  const int* cnt = isS ? scnt : gcnt;
  const int t = threadIdx.x;
  const int i0 = tb * 2048 + 2 * t;
  int v0 = (i0 < n) ? cnt[i0] : 0;
  int v1 = (i0 + 1 < n) ? cnt[i0 + 1] : 0;
  if (!isS) {
    if (i0 < n)     dinv[i0]     = rsqrtf((float)v0 + 2.0f);
    if (i0 + 1 < n) dinv[i0 + 1] = rsqrtf((float)v1 + 2.0f);
  }
  __shared__ int red[16];
  int x = v0 + v1;
  #pragma unroll
  for (int o = 32; o > 0; o >>= 1) x += __shfl_down(x, o);
  const int lane = t & 63, wv = t >> 6;
  if (lane == 0) red[wv] = x;
  __syncthreads();
  if (t < 64) {
    int w = (t < 16) ? red[t] : 0;
    #pragma unroll
    for (int o = 32; o > 0; o >>= 1) w += __shfl_down(w, o);
    if (t == 0) bsum[b] = w;
  }
}

// phase C: per-tile scan + writeback (computes own bsum prefix; nb <= 64)
__global__ __launch_bounds__(1024)
void k_scanC(const int* __restrict__ gcnt, int* __restrict__ goff, int* __restrict__ gcur,
             const int* __restrict__ scnt, int* __restrict__ soff, int* __restrict__ scur,
             const int* __restrict__ bsum, int n, int nb) {
  const int b = blockIdx.x;
  const bool isS = b >= nb;
  const int tb = isS ? b - nb : b;
  const int* cnt = isS ? scnt : gcnt;
  int* off = isS ? soff : goff;
  int* cur = isS ? scur : gcur;
  const int t = threadIdx.x;

  __shared__ int pfx_s;
  if (t < 64) {
    int v = (t < tb) ? bsum[(isS ? nb : 0) + t] : 0;
    v = wave_isum64(v);
    if (t == 0) pfx_s = v;
  }

  const int i0 = tb * 2048 + 2 * t;
  int v0 = (i0 < n) ? cnt[i0] : 0;
  int v1 = (i0 + 1 < n) ? cnt[i0 + 1] : 0;
  int s2 = v0 + v1;
  const int lane = t & 63, wv = t >> 6;
  int x = s2;
  #pragma unroll
  for (int d2 = 1; d2 < 64; d2 <<= 1) {
    int y = __shfl_up(x, d2);
    if (lane >= d2) x += y;
  }
  __shared__ int wsum[16];
  if (lane == 63) wsum[wv] = x;
  __syncthreads();
  if (t < 64) {
    int w = (t < 16) ? wsum[t] : 0;
    #pragma unroll
    for (int d2 = 1; d2 < 16; d2 <<= 1) {
      int y = __shfl_up(w, d2);
      if ((int)t >= d2) w += y;
    }
    if (t < 16) wsum[t] = w;
  }
  __syncthreads();
  int ex = x - s2 + (wv ? wsum[wv - 1] : 0) + pfx_s;
  if (i0 < n)     { cur[i0] = ex;          off[i0 + 1] = ex + v0; }
  if (i0 + 1 < n) { cur[i0 + 1] = ex + v0; off[i0 + 2] = ex + v0 + v1; }
  if (i0 == 0) off[0] = 0;
}

__global__ void k_scatter(const int* __restrict__ src, const int* __restrict__ dst,
                          int* __restrict__ gcur, int* __restrict__ gcsr,
                          int* __restrict__ scur, int* __restrict__ scsr, long E) {
  GS_LOOP(e, E) {
    int s = src[e], d = dst[e];
    int p1 = atomicAdd(&gcur[d], 1); gcsr[p1] = s;
    int p2 = atomicAdd(&scur[s], 1); scsr[p2] = d;
  }
}

// ---------- GEMM: A[n][64] @ W[64][Mtot], 64x64 tile, 4x4 reg tile ----------
// MODE 1: bf16 out16, scaled by rowscale[row]  (hs = (x@Wg)*dinv).
// MODE 2: normalized bf16 rows (out16) + bsc[r] = A_row·W2 + b2.
template <int MODE>
__global__ __launch_bounds__(256)
void k_gemm64v3(const float* __restrict__ A, const float* __restrict__ W,
                float* __restrict__ out32, unsigned short* __restrict__ out16,
                const float* __restrict__ rowscale,
                const float* __restrict__ W2, const float* __restrict__ b2,
                float* __restrict__ bsc, int n, int Mtot) {
  __shared__ float At[64 * GSTRIDE];
  __shared__ float Wl[64 * GSTRIDE];
  const int t  = threadIdx.x;
  const int tx = t & 15;
  const int ty = t >> 4;
  const int col0 = blockIdx.y * 64;
  const long row0 = (long)blockIdx.x * 64;

  #pragma unroll
  for (int i = 0; i < 4; ++i) {
    int k = ty + 16 * i;
    float4 wv = *(const float4*)&W[(long)k * Mtot + col0 + 4 * tx];
    *(float4*)&Wl[k * GSTRIDE + 4 * tx] = wv;
  }
  #pragma unroll
  for (int i = 0; i < 4; ++i) {
    int r = ty + 16 * i;
    long gr = row0 + r; if (gr >= n) gr = n - 1;
    float4 av = *(const float4*)&A[gr * 64 + 4 * tx];
    At[(4 * tx + 0) * GSTRIDE + r] = av.x;
    At[(4 * tx + 1) * GSTRIDE + r] = av.y;
    At[(4 * tx + 2) * GSTRIDE + r] = av.z;
    At[(4 * tx + 3) * GSTRIDE + r] = av.w;
  }
  __syncthreads();

  const int c0 = 4 * tx;
  const int r0 = 4 * ty;
  float acc[4][4] = {};
  #pragma unroll
  for (int k = 0; k < 64; ++k) {
    float4 av = *(const float4*)&At[k * GSTRIDE + r0];
    float4 wv = *(const float4*)&Wl[k * GSTRIDE + c0];
    acc[0][0] = fmaf(av.x, wv.x, acc[0][0]); acc[0][1] = fmaf(av.x, wv.y, acc[0][1]);
    acc[0][2] = fmaf(av.x, wv.z, acc[0][2]); acc[0][3] = fmaf(av.x, wv.w, acc[0][3]);
    acc[1][0] = fmaf(av.y, wv.x, acc[1][0]); acc[1][1] = fmaf(av.y, wv.y, acc[1][1]);
    acc[1][2] = fmaf(av.y, wv.z, acc[1][2]); acc[1][3] = fmaf(av.y, wv.w, acc[1][3]);
    acc[2][0] = fmaf(av.z, wv.x, acc[2][0]); acc[2][1] = fmaf(av.z, wv.y, acc[2][1]);
    acc[2][2] = fmaf(av.z, wv.z, acc[2][2]); acc[2][3] = fmaf(av.z, wv.w, acc[2][3]);
    acc[3][0] = fmaf(av.w, wv.x, acc[3][0]); acc[3][1] = fmaf(av.w, wv.y, acc[3][1]);
    acc[3][2] = fmaf(av.w, wv.z, acc[3][2]); acc[3][3] = fmaf(av.w, wv.w, acc[3][3]);
  }

  if constexpr (MODE == 1) {
    #pragma unroll
    for (int i = 0; i < 4; ++i) {
      long gr = row0 + r0 + i;
      if (gr < n) {
        float sc = rowscale[gr];
        ushort4 v;
        v.x = f2bf(acc[i][0] * sc); v.y = f2bf(acc[i][1] * sc);
        v.z = f2bf(acc[i][2] * sc); v.w = f2bf(acc[i][3] * sc);
        *(ushort4*)&out16[gr * 64 + c0] = v;
      }
    }
  }
  if constexpr (MODE == 2) {
    float p[4], q[4];
    #pragma unroll
    for (int i = 0; i < 4; ++i) {
      q[i] = acc[i][0]*acc[i][0] + acc[i][1]*acc[i][1] +
             acc[i][2]*acc[i][2] + acc[i][3]*acc[i][3];
      p[i] = At[(c0+0) * GSTRIDE + r0 + i] * W2[c0+0] +
             At[(c0+1) * GSTRIDE + r0 + i] * W2[c0+1] +
             At[(c0+2) * GSTRIDE + r0 + i] * W2[c0+2] +
             At[(c0+3) * GSTRIDE + r0 + i] * W2[c0+3];
    }
    #pragma unroll
    for (int m = 1; m < 16; m <<= 1) {
      #pragma unroll
      for (int i = 0; i < 4; ++i) { p[i] += __shfl_xor(p[i], m); q[i] += __shfl_xor(q[i], m); }
    }
    float bb = b2[0];
    #pragma unroll
    for (int i = 0; i < 4; ++i) {
      long gr = row0 + r0 + i;
      if (gr < n) {
        float rn = 1.0f / fmaxf(sqrtf(q[i]), COS_EPS);
        ushort4 v;
        v.x = f2bf(acc[i][0] * rn); v.y = f2bf(acc[i][1] * rn);
        v.z = f2bf(acc[i][2] * rn); v.w = f2bf(acc[i][3] * rn);
        *(ushort4*)&out16[gr * 64 + c0] = v;
        if (tx == 0) bsc[gr] = p[i] + bb;
      }
    }
  }
}

// ---------- h2 GEMM: all 384 cols (6 heads) per block, packed channel-major out.
__global__ __launch_bounds__(256)
void k_gemm_h2(const float* __restrict__ A, const float* __restrict__ W,
               unsigned* __restrict__ h2p, const float* __restrict__ att,
               float* __restrict__ sal, int n) {
  __shared__ float At[64 * GSTRIDE];
  __shared__ float Wl[64 * GSTRIDE];
  const int t  = threadIdx.x;
  const int tx = t & 15;
  const int ty = t >> 4;
  const long row0 = (long)blockIdx.x * 64;
  const int c0 = 4 * tx;
  const int r0 = 4 * ty;

  #pragma unroll
  for (int i = 0; i < 4; ++i) {
    int r = ty + 16 * i;
    long gr = row0 + r; if (gr >= n) gr = n - 1;
    float4 av = *(const float4*)&A[gr * 64 + 4 * tx];
    At[(4 * tx + 0) * GSTRIDE + r] = av.x;
    At[(4 * tx + 1) * GSTRIDE + r] = av.y;
    At[(4 * tx + 2) * GSTRIDE + r] = av.z;
    At[(4 * tx + 3) * GSTRIDE + r] = av.w;
  }
  float4 wr[4];
  #pragma unroll
  for (int i = 0; i < 4; ++i)
    wr[i] = *(const float4*)&W[(long)(ty + 16 * i) * 384 + 4 * tx];

  float4 acc[6][4];
  #pragma unroll
  for (int h = 0; h < 6; ++h)
    #pragma unroll
    for (int i = 0; i < 4; ++i) acc[h][i] = make_float4(0.f, 0.f, 0.f, 0.f);

  #pragma unroll
  for (int head = 0; head < 6; ++head) {
    #pragma unroll
    for (int i = 0; i < 4; ++i)
      *(float4*)&Wl[(ty + 16 * i) * GSTRIDE + 4 * tx] = wr[i];
    __syncthreads();
    if (head < 5) {
      #pragma unroll
      for (int i = 0; i < 4; ++i)
        wr[i] = *(const float4*)&W[(long)(ty + 16 * i) * 384 + (head + 1) * 64 + 4 * tx];
    }
    #pragma unroll 16
    for (int k = 0; k < 64; ++k) {
      float4 av = *(const float4*)&At[k * GSTRIDE + r0];
      float4 wv = *(const float4*)&Wl[k * GSTRIDE + c0];
      acc[head][0].x = fmaf(av.x, wv.x, acc[head][0].x);
      acc[head][0].y = fmaf(av.x, wv.y, acc[head][0].y);
      acc[head][0].z = fmaf(av.x, wv.z, acc[head][0].z);
      acc[head][0].w = fmaf(av.x, wv.w, acc[head][0].w);
      acc[head][1].x = fmaf(av.y, wv.x, acc[head][1].x);
      acc[head][1].y = fmaf(av.y, wv.y, acc[head][1].y);
      acc[head][1].z = fmaf(av.y, wv.z, acc[head][1].z);
      acc[head][1].w = fmaf(av.y, wv.w, acc[head][1].w);
      acc[head][2].x = fmaf(av.z, wv.x, acc[head][2].x);
      acc[head][2].y = fmaf(av.z, wv.y, acc[head][2].y);
      acc[head][2].z = fmaf(av.z, wv.z, acc[head][2].z);
      acc[head][2].w = fmaf(av.z, wv.w, acc[head][2].w);
      acc[head][3].x = fmaf(av.w, wv.x, acc[head][3].x);
      acc[head][3].y = fmaf(av.w, wv.y, acc[head][3].y);
      acc[head][3].z = fmaf(av.w, wv.z, acc[head][3].z);
      acc[head][3].w = fmaf(av.w, wv.w, acc[head][3].w);
    }
    __syncthreads();
  }

  #pragma unroll
  for (int i = 0; i < 4; ++i) {
    long gr = row0 + r0 + i;
    if (gr < n) {
      uint4 u0, u1, u2;
      u0.x = packbf(acc[0][i].x, acc[1][i].x);
      u0.y = packbf(acc[2][i].x, acc[3][i].x);
      u0.z = packbf(acc[4][i].x, acc[5][i].x);
      u0.w = packbf(acc[0][i].y, acc[1][i].y);
      u1.x = packbf(acc[2][i].y, acc[3][i].y);
      u1.y = packbf(acc[4][i].y, acc[5][i].y);
      u1.z = packbf(acc[0][i].z, acc[1][i].z);
      u1.w = packbf(acc[2][i].z, acc[3][i].z);
      u2.x = packbf(acc[4][i].z, acc[5][i].z);
      u2.y = packbf(acc[0][i].w, acc[1][i].w);
      u2.z = packbf(acc[2][i].w, acc[3][i].w);
      u2.w = packbf(acc[4][i].w, acc[5][i].w);
      unsigned* dstp = &h2p[gr * 192 + c0 * 3];
      *(uint4*)(dstp + 0) = u0;
      *(uint4*)(dstp + 4) = u1;
      *(uint4*)(dstp + 8) = u2;
    }
  }
  #pragma unroll
  for (int head = 0; head < 6; ++head) {
    float a0 = att[head * 128 + c0 + 0], a1 = att[head * 128 + c0 + 1];
    float a2 = att[head * 128 + c0 + 2], a3 = att[head * 128 + c0 + 3];
    float p[4];
    #pragma unroll
    for (int i = 0; i < 4; ++i)
      p[i] = acc[head][i].x * a0 + acc[head][i].y * a1 +
             acc[head][i].z * a2 + acc[head][i].w * a3;
    #pragma unroll
    for (int m = 1; m < 16; m <<= 1) {
      #pragma unroll
      for (int i = 0; i < 4; ++i) p[i] += __shfl_xor(p[i], m);
    }
    if (tx == 0) {
      #pragma unroll
      for (int i = 0; i < 4; ++i) {
        long gr = row0 + r0 + i;
        if (gr < n) sal[gr * SALS + head] = p[i];
      }
    }
  }
}

// ---------- GCN aggregate via CSR (wave per node, paired lanes, bf16 rows) ----
__global__ __launch_bounds__(256)
void k_gcnb(const int* __restrict__ goff, const int* __restrict__ gcsr,
            const unsigned* __restrict__ hs32, const float* __restrict__ dinv,
            const float* __restrict__ bg, float* __restrict__ xpj, int n) {
  const int lane = threadIdx.x & 63;
  const int p = lane & 31;
  const int hf = lane >> 5;
  const int d = blockIdx.x * 4 + (threadIdx.x >> 6);
  if (d >= n) return;
  const int o0 = goff[d], o1 = goff[d + 1];
  float ax = 0.f, ay = 0.f;
  for (int j = o0 + hf; j < o1; j += 2) {
    long s = gcsr[j];
    unsigned u = hs32[s * 32 + p];
    ax += bflo(u); ay += bfhi(u);
  }
  ax += __shfl_xor(ax, 32);
  ay += __shfl_xor(ay, 32);
  if (hf == 0) {
    unsigned us = hs32[(long)d * 32 + p];
    float di = dinv[d];
    float2 bv = *(const float2*)&bg[2 * p];
    float2 r;
    r.x = bv.x + di * (ax + 2.0f * bflo(us));
    r.y = bv.y + di * (ay + 2.0f * bfhi(us));
    *(float2*)&xpj[(long)d * 64 + 2 * p] = r;
  }
}

// ---------- fused attention mega-kernel (wave per node; no-max softmax,
// guarded register cache, float2-packed per-head math) ------------------------
__global__ __launch_bounds__(256)
void k_mega(const int* __restrict__ soff, const int* __restrict__ scsr,
            const unsigned* __restrict__ h2p, const float* __restrict__ sal,
            const float* __restrict__ att, float* __restrict__ xm, int n) {
  const int lane = threadIdx.x & 63;
  const int d = blockIdx.x * 4 + (threadIdx.x >> 6);
  if (d >= n) return;
  const int o0 = soff[d], o1 = soff[d + 1];
  const int deg = o1 - o0;       // CSR edges (self excluded)
  const int td  = deg + 1;       // + self
  const float2 z2 = make_float2(0.f, 0.f);
  const float2 ns2 = make_float2(NEG_SLOPE, NEG_SLOPE);

  // ---- pass 1: hmax over self + CSR rows; cache slot 0 = self (guarded) ----
  unsigned ck0[DCACHE], ck1[DCACHE], ck2[DCACHE];
  float2 hm01, hm23, hm45;
  {
    const unsigned* rp = &h2p[(long)d * 192 + lane * 3];
    unsigned u0 = rp[0], u1 = rp[1], u2 = rp[2];
    ck0[0] = u0; ck1[0] = u1; ck2[0] = u2;
    hm01 = up2(u0); hm23 = up2(u1); hm45 = up2(u2);
  }
  #pragma unroll
  for (int idx = 1; idx < DCACHE; ++idx) {
    unsigned u0 = 0, u1 = 0, u2 = 0;
    if (idx < td) {
      long s = scsr[o0 + idx - 1];
      const unsigned* rp = &h2p[s * 192 + lane * 3];
      u0 = rp[0]; u1 = rp[1]; u2 = rp[2];
      hm01 = pk_max(hm01, up2(u0));
      hm23 = pk_max(hm23, up2(u1));
      hm45 = pk_max(hm45, up2(u2));
    }
    ck0[idx] = u0; ck1[idx] = u1; ck2[idx] = u2;
  }
  for (int j = o0 + DCACHE - 1; j < o1; ++j) {
    long s = scsr[j];
    const unsigned* rp = &h2p[s * 192 + lane * 3];
    hm01 = pk_max(hm01, up2(rp[0]));
    hm23 = pk_max(hm23, up2(rp[1]));
    hm45 = pk_max(hm45, up2(rp[2]));
  }

  const float2 attj01 = pk2(att[0 * 128 + 64 + lane], att[1 * 128 + 64 + lane]);
  const float2 attj23 = pk2(att[2 * 128 + 64 + lane], att[3 * 128 + 64 + lane]);
  const float2 attj45 = pk2(att[4 * 128 + 64 + lane], att[5 * 128 + 64 + lane]);
  float2 dal01 = wsum64_f2(pk_mul(hm01, attj01));
  float2 dal23 = wsum64_f2(pk_mul(hm23, attj23));
  float2 dal45 = wsum64_f2(pk_mul(hm45, attj45));
  // softmax shift: per-(node,head) constant K = max(dal, 0) — ratio-invariant
  float2 K01 = pk_max(dal01, z2), K23 = pk_max(dal23, z2), K45 = pk_max(dal45, z2);

  float2 acc01 = z2, acc23 = z2, acc45 = z2;
  float2 den01, den23, den45;

  if (td <= 64) {
    // ---- fast path: lane = edge (0 = self); no max reduction ----
    const bool act = lane < td;
    float4 sA = make_float4(0, 0, 0, 0), sB = sA;
    if (act) {
      int sE = (lane == 0) ? d : scsr[o0 + lane - 1];
      const float4* sp = (const float4*)&sal[(long)sE * SALS];
      sA = sp[0]; sB = sp[1];
    }
    // al = leakyrelu(sal + dal); e = act ? exp(al - K) : 0
    float2 al01 = pk_add(pk2(sA.x, sA.y), dal01);
    float2 al23 = pk_add(pk2(sA.z, sA.w), dal23);
    float2 al45 = pk_add(pk2(sB.x, sB.y), dal45);
    al01 = pk_fma(ns2, pk_min(al01, z2), pk_max(al01, z2));
    al23 = pk_fma(ns2, pk_min(al23, z2), pk_max(al23, z2));
    al45 = pk_fma(ns2, pk_min(al45, z2), pk_max(al45, z2));
    float2 e01, e23, e45;
    e01.x = act ? expf(al01.x - K01.x) : 0.f;
    e01.y = act ? expf(al01.y - K01.y) : 0.f;
    e23.x = act ? expf(al23.x - K23.x) : 0.f;
    e23.y = act ? expf(al23.y - K23.y) : 0.f;
    e45.x = act ? expf(al45.x - K45.x) : 0.f;
    e45.y = act ? expf(al45.y - K45.y) : 0.f;
    den01 = wsum64_f2(e01);
    den23 = wsum64_f2(e23);
    den45 = wsum64_f2(e45);
    // aggregate cached slots (guarded)
    #pragma unroll
    for (int k = 0; k < DCACHE; ++k) {
      if (k < td) {
        float2 w01 = pk2(__shfl(e01.x, k), __shfl(e01.y, k));
        float2 w23 = pk2(__shfl(e23.x, k), __shfl(e23.y, k));
        float2 w45 = pk2(__shfl(e45.x, k), __shfl(e45.y, k));
        acc01 = pk_fma(up2(ck0[k]), w01, acc01);
        acc23 = pk_fma(up2(ck1[k]), w23, acc23);
        acc45 = pk_fma(up2(ck2[k]), w45, acc45);
      }
    }
    // overflow edges: re-read rows
    for (int j = o0 + DCACHE - 1; j < o1; ++j) {
      int ii = j - o0 + 1;              // edge lane index (self = 0)
      long s = scsr[j];
      const unsigned* rp = &h2p[s * 192 + lane * 3];
      unsigned u0 = rp[0], u1 = rp[1], u2 = rp[2];
      float2 w01 = pk2(__shfl(e01.x, ii), __shfl(e01.y, ii));
      float2 w23 = pk2(__shfl(e23.x, ii), __shfl(e23.y, ii));
      float2 w45 = pk2(__shfl(e45.x, ii), __shfl(e45.y, ii));
      acc01 = pk_fma(up2(u0), w01, acc01);
      acc23 = pk_fma(up2(u1), w23, acc23);
      acc45 = pk_fma(up2(u2), w45, acc45);
    }
  } else {
    // ---- slow path (td > 64): single pass, no max pre-pass ----
    {
      const float4* sp = (const float4*)&sal[(long)d * SALS];
      float4 sA = sp[0], sB = sp[1];
      float2 al01 = pk_add(pk2(sA.x, sA.y), dal01);
      float2 al23 = pk_add(pk2(sA.z, sA.w), dal23);
      float2 al45 = pk_add(pk2(sB.x, sB.y), dal45);
      al01 = pk_fma(ns2, pk_min(al01, z2), pk_max(al01, z2));
      al23 = pk_fma(ns2, pk_min(al23, z2), pk_max(al23, z2));
      al45 = pk_fma(ns2, pk_min(al45, z2), pk_max(al45, z2));
      den01 = pk2(expf(al01.x - K01.x), expf(al01.y - K01.y));
      den23 = pk2(expf(al23.x - K23.x), expf(al23.y - K23.y));
      den45 = pk2(expf(al45.x - K45.x), expf(al45.y - K45.y));
    }
    acc01 = pk_mul(up2(ck0[0]), den01);
    acc23 = pk_mul(up2(ck1[0]), den23);
    acc45 = pk_mul(up2(ck2[0]), den45);
    for (int base = o0; base < o1; base += 64) {
      int cs = o1 - base; if (cs > 64) cs = 64;
      int j = base + lane;
      float2 e01 = z2, e23 = z2, e45 = z2;
      int s = 0;
      if (j < o1) {
        s = scsr[j];
        const float4* sp = (const float4*)&sal[(long)s * SALS];
        float4 sA = sp[0], sB = sp[1];
        float2 al01 = pk_add(pk2(sA.x, sA.y), dal01);
        float2 al23 = pk_add(pk2(sA.z, sA.w), dal23);
        float2 al45 = pk_add(pk2(sB.x, sB.y), dal45);
        al01 = pk_fma(ns2, pk_min(al01, z2), pk_max(al01, z2));
        al23 = pk_fma(ns2, pk_min(al23, z2), pk_max(al23, z2));
        al45 = pk_fma(ns2, pk_min(al45, z2), pk_max(al45, z2));
        e01 = pk2(expf(al01.x - K01.x), expf(al01.y - K01.y));
        e23 = pk2(expf(al23.x - K23.x), expf(al23.y - K23.y));
        e45 = pk2(expf(al45.x - K45.x), expf(al45.y - K45.y));
      }
      den01 = pk_add(den01, wsum64_f2(e01));
      den23 = pk_add(den23, wsum64_f2(e23));
      den45 = pk_add(den45, wsum64_f2(e45));
      for (int jj = 0; jj < cs; ++jj) {
        int sj = __shfl(s, jj);
        const unsigned* rp = &h2p[(long)sj * 192 + lane * 3];
        unsigned u0 = rp[0], u1 = rp[1], u2 = rp[2];
        float2 w01 = pk2(__shfl(e01.x, jj), __shfl(e01.y, jj));
        float2 w23 = pk2(__shfl(e23.x, jj), __shfl(e23.y, jj));
        float2 w45 = pk2(__shfl(e45.x, jj), __shfl(e45.y, jj));
        acc01 = pk_fma(up2(u0), w01, acc01);
        acc23 = pk_fma(up2(u1), w23, acc23);
        acc45 = pk_fma(up2(u2), w45, acc45);
      }
    }
  }

  float o = acc01.x / den01.x + acc01.y / den01.y +
            acc23.x / den23.x + acc23.y / den23.y +
            acc45.x / den45.x + acc45.y / den45.y;
  xm[(long)d * 64 + lane] = o * (1.0f / NH);
}

// fitness[d] = sigmoid(bsc[d] * (1 + sum_CSR dot(an[s], an[d])))
__global__ __launch_bounds__(256)
void k_cosout(const int* __restrict__ soff, const int* __restrict__ scsr,
              const unsigned* __restrict__ an32, const float* __restrict__ bsc,
              float* __restrict__ out, int n) {
  const int lane = threadIdx.x & 63;
  const int p = lane & 31;
  const int hf = lane >> 5;
  const int d = blockIdx.x * 4 + (threadIdx.x >> 6);
  if (d >= n) return;
  const int o0 = soff[d], o1 = soff[d + 1];
  unsigned ud = an32[(long)d * 32 + p];
  float adx = bflo(ud), ady = bfhi(ud);
  float cl = 0.f;
  for (int j = o0 + hf; j < o1; j += 2) {
    long s = scsr[j];
    unsigned u = an32[s * 32 + p];
    cl += adx * bflo(u) + ady * bfhi(u);
  }
  float cs = wave_sum64(cl) + 1.0f;   // self-cosine == 1 exactly
  if (lane == 0) out[d] = 1.0f / (1.0f + expf(-bsc[d] * cs));
}

// ---------- launcher ----------
static inline unsigned gsblocks(long total) {
  long b = (total + TPB - 1) / TPB;
  if (b > 131072) b = 131072;
  return (unsigned)b;
}

extern "C" void kernel_launch(void* const* d_in, const int* in_sizes, int n_in,
                              void* d_out, int out_size, void* d_ws, size_t ws_size,
                              hipStream_t stream) {
  const float* x   = (const float*)d_in[0];
  const float* Wg  = (const float*)d_in[1];
  const float* bg  = (const float*)d_in[2];
  const float* Wt  = (const float*)d_in[3];
  const float* att = (const float*)d_in[4];
  const float* W1  = (const float*)d_in[5];
  const float* W2  = (const float*)d_in[6];
  const float* b2  = (const float*)d_in[7];
  const int* src   = (const int*)d_in[8];
  const int* dst   = (const int*)d_in[9];

  const long n   = in_sizes[0] / 64;   // 50000
  const long en  = in_sizes[8];        // E + N
  const long E   = en - n;             // real edges (ei), loops excluded
  const int  nb  = (int)((n + 2047) / 2048);

  char* base = (char*)d_ws;
  size_t off = 0;
  auto alloc = [&](size_t bytes) -> void* {
    void* p = base + off;
    off += (bytes + 255) & ~(size_t)255;
    return p;
  };
  int*   gcnt = (int*)alloc(n * 4);
  int*   scnt = (int*)alloc(n * 4);   // contiguous with gcnt (one memset)
  int*   goff = (int*)alloc((n + 1) * 4);
  int*   soff = (int*)alloc((n + 1) * 4);
  int*   gcur = (int*)alloc(n * 4);
  int*   scur = (int*)alloc(n * 4);
  int*   gcsr = (int*)alloc(E * 4);
  int*   scsr = (int*)alloc(E * 4);
  int*   bsum = (int*)alloc(2 * (size_t)nb * 4);
  float* dinv = (float*)alloc(n * 4);
  unsigned* hs32 = (unsigned*)alloc(n * 32 * 4);      // bf16 pairs of (x@Wg)*dinv
  float* xpj  = (float*)alloc(n * 64 * 4);            // later anorm (bf16)
  float* xmb  = (float*)alloc(n * 64 * 4);            // xm buffer
  unsigned* h2p = (unsigned*)alloc(n * 192 * 4);      // channel-major bf16 pairs
  float* sal  = (float*)alloc(n * SALS * 4);
  float* bsc  = (float*)alloc(n * 4);
  unsigned short* anorm = (unsigned short*)xpj;       // alias (xpj dead after h2)
  float* out  = (float*)d_out;

  const unsigned rowblk  = (unsigned)((n + 63) / 64);
  const unsigned nodeblk = (unsigned)((n + 3) / 4);

  // ---- CSR build (E edges only; self-loops analytic) + dinv ----
  hipMemsetAsync(gcnt, 0, (size_t)((char*)scnt - (char*)gcnt) + n * 4, stream);
  k_cnt<<<gsblocks(E), TPB, 0, stream>>>(src, dst, gcnt, scnt, E);
  k_scanA<<<2 * nb, 1024, 0, stream>>>(gcnt, scnt, bsum, dinv, (int)n, nb);
  k_scanC<<<2 * nb, 1024, 0, stream>>>(gcnt, goff, gcur, scnt, soff, scur,
                                       bsum, (int)n, nb);
  k_scatter<<<gsblocks(E), TPB, 0, stream>>>(src, dst, gcur, gcsr, scur, scsr, E);

  // ---- hs = (x @ W_gcn) * dinv[row], bf16 ----
  { dim3 g(rowblk, 1);
    k_gemm64v3<1><<<g, 256, 0, stream>>>(x, Wg, nullptr, (unsigned short*)hs32,
                                         dinv, nullptr, nullptr, nullptr, (int)n, 64); }

  // ---- xpj = bg + dinv[d] * (2*hs[d] + sum_CSR hs[s]) ----
  k_gcnb<<<nodeblk, 256, 0, stream>>>(goff, gcsr, hs32, dinv, bg, xpj, (int)n);

  // ---- h2 = xpj @ weight (bf16 channel-major packed) + fused sal ----
  k_gemm_h2<<<rowblk, 256, 0, stream>>>(xpj, Wt, h2p, att, sal, (int)n);

  // ---- fused attention (self inline, no-max softmax, packed math) -> xm ----
  k_mega<<<nodeblk, 256, 0, stream>>>(soff, scsr, h2p, sal, att, xmb, (int)n);

  // ---- a = normalize(xm @ W1) (bf16, aliases xpj) + bsc ----
  { dim3 g(rowblk, 1);
    k_gemm64v3<2><<<g, 256, 0, stream>>>(xmb, W1, nullptr, anorm, nullptr,
                                         W2, b2, bsc, (int)n, 64); }

  // ---- cosine + sigmoid -> out (self-cos = 1 analytic) ----
  k_cosout<<<nodeblk, 256, 0, stream>>>(soff, scsr, (const unsigned*)anorm,
                                        bsc, out, (int)n);
}

// Round 15
// 347.533 us; speedup vs baseline: 1.1681x; 1.0197x over previous
//
#include <hip/hip_runtime.h>
#include <math.h>

#define TPB 256
#define NEG_SLOPE 0.2f
#define COS_EPS 1e-8f
#define NH 6
#define GSTRIDE 68   // LDS row stride (floats) for GEMM tiles
#define DCACHE 16    // rows cached in registers per node (slot 0 = self), guarded
#define SALS 8       // sal row stride (floats), 32B-aligned

// ---------- helpers ----------
__device__ inline float wave_sum64(float v) {
  #pragma unroll
  for (int off = 32; off > 0; off >>= 1) v += __shfl_down(v, off);
  return __shfl(v, 0);
}
__device__ inline int wave_isum64(int v) {
  #pragma unroll
  for (int off = 32; off > 0; off >>= 1) v += __shfl_down(v, off);
  return v;   // valid in lane 0
}
__device__ inline unsigned short f2bf(float f) {
  unsigned u = __float_as_uint(f);
  unsigned r = (u + 0x7fffu + ((u >> 16) & 1u)) >> 16;   // RNE
  return (unsigned short)r;
}
__device__ inline float bf2f(unsigned short b) {
  return __uint_as_float(((unsigned)b) << 16);
}
__device__ inline unsigned packbf(float lo, float hi) {
  return (unsigned)f2bf(lo) | ((unsigned)f2bf(hi) << 16);
}
__device__ inline float bflo(unsigned u) { return __uint_as_float(u << 16); }
__device__ inline float bfhi(unsigned u) { return __uint_as_float(u & 0xffff0000u); }

// float2 packed-math helpers (target: v_pk_*_f32 on CDNA4)
__device__ inline float2 pk2(float a, float b) { return make_float2(a, b); }
__device__ inline float2 up2(unsigned u) { return make_float2(bflo(u), bfhi(u)); }
__device__ inline float2 pk_add(float2 a, float2 b) { return make_float2(a.x + b.x, a.y + b.y); }
__device__ inline float2 pk_mul(float2 a, float2 b) { return make_float2(a.x * b.x, a.y * b.y); }
__device__ inline float2 pk_max(float2 a, float2 b) { return make_float2(fmaxf(a.x, b.x), fmaxf(a.y, b.y)); }
__device__ inline float2 pk_min(float2 a, float2 b) { return make_float2(fminf(a.x, b.x), fminf(a.y, b.y)); }
__device__ inline float2 pk_fma(float2 a, float2 b, float2 c) {
  return make_float2(fmaf(a.x, b.x, c.x), fmaf(a.y, b.y, c.y));
}
__device__ inline float2 wsum64_f2(float2 v) {
  #pragma unroll
  for (int off = 32; off > 0; off >>= 1) {
    v.x += __shfl_down(v.x, off);
    v.y += __shfl_down(v.y, off);
  }
  v.x = __shfl(v.x, 0); v.y = __shfl(v.y, 0);
  return v;
}

#define GS_LOOP(i, total) \
  for (long i = (long)blockIdx.x * blockDim.x + threadIdx.x; i < (total); \
       i += (long)gridDim.x * blockDim.x)

// ---------- CSR build: ONLY the E real edges (self-loops handled analytically)
__global__ void k_cnt(const int* __restrict__ src, const int* __restrict__ dst,
                      int* __restrict__ gcnt, int* __restrict__ scnt, long E) {
  GS_LOOP(e, E) {
    atomicAdd(&gcnt[dst[e]], 1);
    atomicAdd(&scnt[src[e]], 1);
  }
}

// phase A: per-tile sums + dinv = rsqrt(gcnt + 2)
__global__ __launch_bounds__(1024)
void k_scanA(const int* __restrict__ gcnt, const int* __restrict__ scnt,
             int* __restrict__ bsum, float* __restrict__ dinv, int n, int nb) {
  const int b = blockIdx.x;
  const bool isS = b >= nb;
  const int tb = isS ? b - nb : b;
  const int* cnt = isS ? scnt : gcnt;
  const int t = threadIdx.x;
  const int i0 = tb * 2048 + 2 * t;
  int v0 = (i0 < n) ? cnt[i0] : 0;
  int v1 = (i0 + 1 < n) ? cnt[i0 + 1] : 0;
  if (!isS) {
    if (i0 < n)     dinv[i0]     = rsqrtf((float)v0 + 2.0f);
    if (i0 + 1 < n) dinv[i0 + 1] = rsqrtf((float)v1 + 2.0f);
  }
  __shared__ int red[16];
  int x = v0 + v1;
  #pragma unroll
  for (int o = 32; o > 0; o >>= 1) x += __shfl_down(x, o);
  const int lane = t & 63, wv = t >> 6;
  if (lane == 0) red[wv] = x;
  __syncthreads();
  if (t < 64) {
    int w = (t < 16) ? red[t] : 0;
    #pragma unroll
    for (int o = 32; o > 0; o >>= 1) w += __shfl_down(w, o);
    if (t == 0) bsum[b] = w;
  }
}

// phase C: per-tile scan + writeback (computes own bsum prefix; nb <= 64)
__global__ __launch_bounds__(1024)
void k_scanC(const int* __restrict__ gcnt, int* __restrict__ goff, int* __restrict__ gcur,
             const int* __restrict__ scnt, int* __restrict__ soff, int* __restrict__ scur,
             const int* __restrict__ bsum, int n, int nb) {
  const int b = blockIdx.x;
  const bool isS = b >= nb;
  const int tb = isS ? b - nb : b;
  const int* cnt = isS ? scnt : gcnt;
  int* off = isS ? soff : goff;
  int* cur = isS ? scur : gcur;
  const int t = threadIdx.x;

  __shared__ int pfx_s;
  if (t < 64) {
    int v = (t < tb) ? bsum[(isS ? nb : 0) + t] : 0;
    v = wave_isum64(v);
    if (t == 0) pfx_s = v;
  }

  const int i0 = tb * 2048 + 2 * t;
  int v0 = (i0 < n) ? cnt[i0] : 0;
  int v1 = (i0 + 1 < n) ? cnt[i0 + 1] : 0;
  int s2 = v0 + v1;
  const int lane = t & 63, wv = t >> 6;
  int x = s2;
  #pragma unroll
  for (int d2 = 1; d2 < 64; d2 <<= 1) {
    int y = __shfl_up(x, d2);
    if (lane >= d2) x += y;
  }
  __shared__ int wsum[16];
  if (lane == 63) wsum[wv] = x;
  __syncthreads();
  if (t < 64) {
    int w = (t < 16) ? wsum[t] : 0;
    #pragma unroll
    for (int d2 = 1; d2 < 16; d2 <<= 1) {
      int y = __shfl_up(w, d2);
      if ((int)t >= d2) w += y;
    }
    if (t < 16) wsum[t] = w;
  }
  __syncthreads();
  int ex = x - s2 + (wv ? wsum[wv - 1] : 0) + pfx_s;
  if (i0 < n)     { cur[i0] = ex;          off[i0 + 1] = ex + v0; }
  if (i0 + 1 < n) { cur[i0 + 1] = ex + v0; off[i0 + 2] = ex + v0 + v1; }
  if (i0 == 0) off[0] = 0;
}

__global__ void k_scatter(const int* __restrict__ src, const int* __restrict__ dst,
                          int* __restrict__ gcur, int* __restrict__ gcsr,
                          int* __restrict__ scur, int* __restrict__ scsr, long E) {
  GS_LOOP(e, E) {
    int s = src[e], d = dst[e];
    int p1 = atomicAdd(&gcur[d], 1); gcsr[p1] = s;
    int p2 = atomicAdd(&scur[s], 1); scsr[p2] = d;
  }
}

// ---------- GEMM: A[n][64] @ W[64][Mtot], 64x64 tile, 4x4 reg tile ----------
// MODE 1: bf16 out16, scaled by rowscale[row]  (hs = (x@Wg)*dinv).
// MODE 2: normalized bf16 rows (out16) + bsc[r] = A_row·W2 + b2.
template <int MODE>
__global__ __launch_bounds__(256)
void k_gemm64v3(const float* __restrict__ A, const float* __restrict__ W,
                float* __restrict__ out32, unsigned short* __restrict__ out16,
                const float* __restrict__ rowscale,
                const float* __restrict__ W2, const float* __restrict__ b2,
                float* __restrict__ bsc, int n, int Mtot) {
  __shared__ float At[64 * GSTRIDE];
  __shared__ float Wl[64 * GSTRIDE];
  const int t  = threadIdx.x;
  const int tx = t & 15;
  const int ty = t >> 4;
  const int col0 = blockIdx.y * 64;
  const long row0 = (long)blockIdx.x * 64;

  #pragma unroll
  for (int i = 0; i < 4; ++i) {
    int k = ty + 16 * i;
    float4 wv = *(const float4*)&W[(long)k * Mtot + col0 + 4 * tx];
    *(float4*)&Wl[k * GSTRIDE + 4 * tx] = wv;
  }
  #pragma unroll
  for (int i = 0; i < 4; ++i) {
    int r = ty + 16 * i;
    long gr = row0 + r; if (gr >= n) gr = n - 1;
    float4 av = *(const float4*)&A[gr * 64 + 4 * tx];
    At[(4 * tx + 0) * GSTRIDE + r] = av.x;
    At[(4 * tx + 1) * GSTRIDE + r] = av.y;
    At[(4 * tx + 2) * GSTRIDE + r] = av.z;
    At[(4 * tx + 3) * GSTRIDE + r] = av.w;
  }
  __syncthreads();

  const int c0 = 4 * tx;
  const int r0 = 4 * ty;
  float acc[4][4] = {};
  #pragma unroll
  for (int k = 0; k < 64; ++k) {
    float4 av = *(const float4*)&At[k * GSTRIDE + r0];
    float4 wv = *(const float4*)&Wl[k * GSTRIDE + c0];
    acc[0][0] = fmaf(av.x, wv.x, acc[0][0]); acc[0][1] = fmaf(av.x, wv.y, acc[0][1]);
    acc[0][2] = fmaf(av.x, wv.z, acc[0][2]); acc[0][3] = fmaf(av.x, wv.w, acc[0][3]);
    acc[1][0] = fmaf(av.y, wv.x, acc[1][0]); acc[1][1] = fmaf(av.y, wv.y, acc[1][1]);
    acc[1][2] = fmaf(av.y, wv.z, acc[1][2]); acc[1][3] = fmaf(av.y, wv.w, acc[1][3]);
    acc[2][0] = fmaf(av.z, wv.x, acc[2][0]); acc[2][1] = fmaf(av.z, wv.y, acc[2][1]);
    acc[2][2] = fmaf(av.z, wv.z, acc[2][2]); acc[2][3] = fmaf(av.z, wv.w, acc[2][3]);
    acc[3][0] = fmaf(av.w, wv.x, acc[3][0]); acc[3][1] = fmaf(av.w, wv.y, acc[3][1]);
    acc[3][2] = fmaf(av.w, wv.z, acc[3][2]); acc[3][3] = fmaf(av.w, wv.w, acc[3][3]);
  }

  if constexpr (MODE == 1) {
    #pragma unroll
    for (int i = 0; i < 4; ++i) {
      long gr = row0 + r0 + i;
      if (gr < n) {
        float sc = rowscale[gr];
        ushort4 v;
        v.x = f2bf(acc[i][0] * sc); v.y = f2bf(acc[i][1] * sc);
        v.z = f2bf(acc[i][2] * sc); v.w = f2bf(acc[i][3] * sc);
        *(ushort4*)&out16[gr * 64 + c0] = v;
      }
    }
  }
  if constexpr (MODE == 2) {
    float p[4], q[4];
    #pragma unroll
    for (int i = 0; i < 4; ++i) {
      q[i] = acc[i][0]*acc[i][0] + acc[i][1]*acc[i][1] +
             acc[i][2]*acc[i][2] + acc[i][3]*acc[i][3];
      p[i] = At[(c0+0) * GSTRIDE + r0 + i] * W2[c0+0] +
             At[(c0+1) * GSTRIDE + r0 + i] * W2[c0+1] +
             At[(c0+2) * GSTRIDE + r0 + i] * W2[c0+2] +
             At[(c0+3) * GSTRIDE + r0 + i] * W2[c0+3];
    }
    #pragma unroll
    for (int m = 1; m < 16; m <<= 1) {
      #pragma unroll
      for (int i = 0; i < 4; ++i) { p[i] += __shfl_xor(p[i], m); q[i] += __shfl_xor(q[i], m); }
    }
    float bb = b2[0];
    #pragma unroll
    for (int i = 0; i < 4; ++i) {
      long gr = row0 + r0 + i;
      if (gr < n) {
        float rn = 1.0f / fmaxf(sqrtf(q[i]), COS_EPS);
        ushort4 v;
        v.x = f2bf(acc[i][0] * rn); v.y = f2bf(acc[i][1] * rn);
        v.z = f2bf(acc[i][2] * rn); v.w = f2bf(acc[i][3] * rn);
        *(ushort4*)&out16[gr * 64 + c0] = v;
        if (tx == 0) bsc[gr] = p[i] + bb;
      }
    }
  }
}

// ---------- h2 GEMM: all 384 cols (6 heads) per block, packed channel-major out.
__global__ __launch_bounds__(256)
void k_gemm_h2(const float* __restrict__ A, const float* __restrict__ W,
               unsigned* __restrict__ h2p, const float* __restrict__ att,
               float* __restrict__ sal, int n) {
  __shared__ float At[64 * GSTRIDE];
  __shared__ float Wl[64 * GSTRIDE];
  const int t  = threadIdx.x;
  const int tx = t & 15;
  const int ty = t >> 4;
  const long row0 = (long)blockIdx.x * 64;
  const int c0 = 4 * tx;
  const int r0 = 4 * ty;

  #pragma unroll
  for (int i = 0; i < 4; ++i) {
    int r = ty + 16 * i;
    long gr = row0 + r; if (gr >= n) gr = n - 1;
    float4 av = *(const float4*)&A[gr * 64 + 4 * tx];
    At[(4 * tx + 0) * GSTRIDE + r] = av.x;
    At[(4 * tx + 1) * GSTRIDE + r] = av.y;
    At[(4 * tx + 2) * GSTRIDE + r] = av.z;
    At[(4 * tx + 3) * GSTRIDE + r] = av.w;
  }
  float4 wr[4];
  #pragma unroll
  for (int i = 0; i < 4; ++i)
    wr[i] = *(const float4*)&W[(long)(ty + 16 * i) * 384 + 4 * tx];

  float4 acc[6][4];
  #pragma unroll
  for (int h = 0; h < 6; ++h)
    #pragma unroll
    for (int i = 0; i < 4; ++i) acc[h][i] = make_float4(0.f, 0.f, 0.f, 0.f);

  #pragma unroll
  for (int head = 0; head < 6; ++head) {
    #pragma unroll
    for (int i = 0; i < 4; ++i)
      *(float4*)&Wl[(ty + 16 * i) * GSTRIDE + 4 * tx] = wr[i];
    __syncthreads();
    if (head < 5) {
      #pragma unroll
      for (int i = 0; i < 4; ++i)
        wr[i] = *(const float4*)&W[(long)(ty + 16 * i) * 384 + (head + 1) * 64 + 4 * tx];
    }
    #pragma unroll 16
    for (int k = 0; k < 64; ++k) {
      float4 av = *(const float4*)&At[k * GSTRIDE + r0];
      float4 wv = *(const float4*)&Wl[k * GSTRIDE + c0];
      acc[head][0].x = fmaf(av.x, wv.x, acc[head][0].x);
      acc[head][0].y = fmaf(av.x, wv.y, acc[head][0].y);
      acc[head][0].z = fmaf(av.x, wv.z, acc[head][0].z);
      acc[head][0].w = fmaf(av.x, wv.w, acc[head][0].w);
      acc[head][1].x = fmaf(av.y, wv.x, acc[head][1].x);
      acc[head][1].y = fmaf(av.y, wv.y, acc[head][1].y);
      acc[head][1].z = fmaf(av.y, wv.z, acc[head][1].z);
      acc[head][1].w = fmaf(av.y, wv.w, acc[head][1].w);
      acc[head][2].x = fmaf(av.z, wv.x, acc[head][2].x);
      acc[head][2].y = fmaf(av.z, wv.y, acc[head][2].y);
      acc[head][2].z = fmaf(av.z, wv.z, acc[head][2].z);
      acc[head][2].w = fmaf(av.z, wv.w, acc[head][2].w);
      acc[head][3].x = fmaf(av.w, wv.x, acc[head][3].x);
      acc[head][3].y = fmaf(av.w, wv.y, acc[head][3].y);
      acc[head][3].z = fmaf(av.w, wv.z, acc[head][3].z);
      acc[head][3].w = fmaf(av.w, wv.w, acc[head][3].w);
    }
    __syncthreads();
  }

  #pragma unroll
  for (int i = 0; i < 4; ++i) {
    long gr = row0 + r0 + i;
    if (gr < n) {
      uint4 u0, u1, u2;
      u0.x = packbf(acc[0][i].x, acc[1][i].x);
      u0.y = packbf(acc[2][i].x, acc[3][i].x);
      u0.z = packbf(acc[4][i].x, acc[5][i].x);
      u0.w = packbf(acc[0][i].y, acc[1][i].y);
      u1.x = packbf(acc[2][i].y, acc[3][i].y);
      u1.y = packbf(acc[4][i].y, acc[5][i].y);
      u1.z = packbf(acc[0][i].z, acc[1][i].z);
      u1.w = packbf(acc[2][i].z, acc[3][i].z);
      u2.x = packbf(acc[4][i].z, acc[5][i].z);
      u2.y = packbf(acc[0][i].w, acc[1][i].w);
      u2.z = packbf(acc[2][i].w, acc[3][i].w);
      u2.w = packbf(acc[4][i].w, acc[5][i].w);
      unsigned* dstp = &h2p[gr * 192 + c0 * 3];
      *(uint4*)(dstp + 0) = u0;
      *(uint4*)(dstp + 4) = u1;
      *(uint4*)(dstp + 8) = u2;
    }
  }
  #pragma unroll
  for (int head = 0; head < 6; ++head) {
    float a0 = att[head * 128 + c0 + 0], a1 = att[head * 128 + c0 + 1];
    float a2 = att[head * 128 + c0 + 2], a3 = att[head * 128 + c0 + 3];
    float p[4];
    #pragma unroll
    for (int i = 0; i < 4; ++i)
      p[i] = acc[head][i].x * a0 + acc[head][i].y * a1 +
             acc[head][i].z * a2 + acc[head][i].w * a3;
    #pragma unroll
    for (int m = 1; m < 16; m <<= 1) {
      #pragma unroll
      for (int i = 0; i < 4; ++i) p[i] += __shfl_xor(p[i], m);
    }
    if (tx == 0) {
      #pragma unroll
      for (int i = 0; i < 4; ++i) {
        long gr = row0 + r0 + i;
        if (gr < n) sal[gr * SALS + head] = p[i];
      }
    }
  }
}

// ---------- GCN aggregate via CSR (wave per node, 4 concurrent edges,
// 16 lanes x uint2 per 128B row) ----------------------------------------------
__global__ __launch_bounds__(256)
void k_gcnb(const int* __restrict__ goff, const int* __restrict__ gcsr,
            const unsigned* __restrict__ hs32, const float* __restrict__ dinv,
            const float* __restrict__ bg, float* __restrict__ xpj, int n) {
  const int lane = threadIdx.x & 63;
  const int p = lane & 15;       // channel quad (2 dwords = 4 channels)
  const int hf = lane >> 4;      // which of 4 concurrent edges
  const int d = blockIdx.x * 4 + (threadIdx.x >> 6);
  if (d >= n) return;
  const int o0 = goff[d], o1 = goff[d + 1];
  float a0 = 0.f, a1 = 0.f, a2 = 0.f, a3 = 0.f;
  for (int j = o0 + hf; j < o1; j += 4) {
    long s = gcsr[j];
    uint2 u = *(const uint2*)&hs32[s * 32 + 2 * p];
    a0 += bflo(u.x); a1 += bfhi(u.x);
    a2 += bflo(u.y); a3 += bfhi(u.y);
  }
  a0 += __shfl_xor(a0, 16); a1 += __shfl_xor(a1, 16);
  a2 += __shfl_xor(a2, 16); a3 += __shfl_xor(a3, 16);
  a0 += __shfl_xor(a0, 32); a1 += __shfl_xor(a1, 32);
  a2 += __shfl_xor(a2, 32); a3 += __shfl_xor(a3, 32);
  if (hf == 0) {
    uint2 us = *(const uint2*)&hs32[(long)d * 32 + 2 * p];
    float di = dinv[d];
    float4 bv = *(const float4*)&bg[4 * p];
    float4 r;
    r.x = bv.x + di * (a0 + 2.0f * bflo(us.x));
    r.y = bv.y + di * (a1 + 2.0f * bfhi(us.x));
    r.z = bv.z + di * (a2 + 2.0f * bflo(us.y));
    r.w = bv.w + di * (a3 + 2.0f * bfhi(us.y));
    *(float4*)&xpj[(long)d * 64 + 4 * p] = r;
  }
}

// ---------- fused attention mega-kernel (wave per node; no-max softmax,
// guarded register cache, float2-packed per-head math) ------------------------
__global__ __launch_bounds__(256)
void k_mega(const int* __restrict__ soff, const int* __restrict__ scsr,
            const unsigned* __restrict__ h2p, const float* __restrict__ sal,
            const float* __restrict__ att, float* __restrict__ xm, int n) {
  const int lane = threadIdx.x & 63;
  const int d = blockIdx.x * 4 + (threadIdx.x >> 6);
  if (d >= n) return;
  const int o0 = soff[d], o1 = soff[d + 1];
  const int deg = o1 - o0;       // CSR edges (self excluded)
  const int td  = deg + 1;       // + self
  const float2 z2 = make_float2(0.f, 0.f);
  const float2 ns2 = make_float2(NEG_SLOPE, NEG_SLOPE);

  // ---- pass 1: hmax over self + CSR rows; cache slot 0 = self (guarded) ----
  unsigned ck0[DCACHE], ck1[DCACHE], ck2[DCACHE];
  float2 hm01, hm23, hm45;
  {
    const unsigned* rp = &h2p[(long)d * 192 + lane * 3];
    unsigned u0 = rp[0], u1 = rp[1], u2 = rp[2];
    ck0[0] = u0; ck1[0] = u1; ck2[0] = u2;
    hm01 = up2(u0); hm23 = up2(u1); hm45 = up2(u2);
  }
  #pragma unroll
  for (int idx = 1; idx < DCACHE; ++idx) {
    unsigned u0 = 0, u1 = 0, u2 = 0;
    if (idx < td) {
      long s = scsr[o0 + idx - 1];
      const unsigned* rp = &h2p[s * 192 + lane * 3];
      u0 = rp[0]; u1 = rp[1]; u2 = rp[2];
      hm01 = pk_max(hm01, up2(u0));
      hm23 = pk_max(hm23, up2(u1));
      hm45 = pk_max(hm45, up2(u2));
    }
    ck0[idx] = u0; ck1[idx] = u1; ck2[idx] = u2;
  }
  for (int j = o0 + DCACHE - 1; j < o1; ++j) {
    long s = scsr[j];
    const unsigned* rp = &h2p[s * 192 + lane * 3];
    hm01 = pk_max(hm01, up2(rp[0]));
    hm23 = pk_max(hm23, up2(rp[1]));
    hm45 = pk_max(hm45, up2(rp[2]));
  }

  const float2 attj01 = pk2(att[0 * 128 + 64 + lane], att[1 * 128 + 64 + lane]);
  const float2 attj23 = pk2(att[2 * 128 + 64 + lane], att[3 * 128 + 64 + lane]);
  const float2 attj45 = pk2(att[4 * 128 + 64 + lane], att[5 * 128 + 64 + lane]);
  float2 dal01 = wsum64_f2(pk_mul(hm01, attj01));
  float2 dal23 = wsum64_f2(pk_mul(hm23, attj23));
  float2 dal45 = wsum64_f2(pk_mul(hm45, attj45));
  // softmax shift: per-(node,head) constant K = max(dal, 0) — ratio-invariant
  float2 K01 = pk_max(dal01, z2), K23 = pk_max(dal23, z2), K45 = pk_max(dal45, z2);

  float2 acc01 = z2, acc23 = z2, acc45 = z2;
  float2 den01, den23, den45;

  if (td <= 64) {
    // ---- fast path: lane = edge (0 = self); no max reduction ----
    const bool act = lane < td;
    float4 sA = make_float4(0, 0, 0, 0), sB = sA;
    if (act) {
      int sE = (lane == 0) ? d : scsr[o0 + lane - 1];
      const float4* sp = (const float4*)&sal[(long)sE * SALS];
      sA = sp[0]; sB = sp[1];
    }
    // al = leakyrelu(sal + dal); e = act ? exp(al - K) : 0
    float2 al01 = pk_add(pk2(sA.x, sA.y), dal01);
    float2 al23 = pk_add(pk2(sA.z, sA.w), dal23);
    float2 al45 = pk_add(pk2(sB.x, sB.y), dal45);
    al01 = pk_fma(ns2, pk_min(al01, z2), pk_max(al01, z2));
    al23 = pk_fma(ns2, pk_min(al23, z2), pk_max(al23, z2));
    al45 = pk_fma(ns2, pk_min(al45, z2), pk_max(al45, z2));
    float2 e01, e23, e45;
    e01.x = act ? expf(al01.x - K01.x) : 0.f;
    e01.y = act ? expf(al01.y - K01.y) : 0.f;
    e23.x = act ? expf(al23.x - K23.x) : 0.f;
    e23.y = act ? expf(al23.y - K23.y) : 0.f;
    e45.x = act ? expf(al45.x - K45.x) : 0.f;
    e45.y = act ? expf(al45.y - K45.y) : 0.f;
    den01 = wsum64_f2(e01);
    den23 = wsum64_f2(e23);
    den45 = wsum64_f2(e45);
    // aggregate cached slots (guarded)
    #pragma unroll
    for (int k = 0; k < DCACHE; ++k) {
      if (k < td) {
        float2 w01 = pk2(__shfl(e01.x, k), __shfl(e01.y, k));
        float2 w23 = pk2(__shfl(e23.x, k), __shfl(e23.y, k));
        float2 w45 = pk2(__shfl(e45.x, k), __shfl(e45.y, k));
        acc01 = pk_fma(up2(ck0[k]), w01, acc01);
        acc23 = pk_fma(up2(ck1[k]), w23, acc23);
        acc45 = pk_fma(up2(ck2[k]), w45, acc45);
      }
    }
    // overflow edges: re-read rows
    for (int j = o0 + DCACHE - 1; j < o1; ++j) {
      int ii = j - o0 + 1;              // edge lane index (self = 0)
      long s = scsr[j];
      const unsigned* rp = &h2p[s * 192 + lane * 3];
      unsigned u0 = rp[0], u1 = rp[1], u2 = rp[2];
      float2 w01 = pk2(__shfl(e01.x, ii), __shfl(e01.y, ii));
      float2 w23 = pk2(__shfl(e23.x, ii), __shfl(e23.y, ii));
      float2 w45 = pk2(__shfl(e45.x, ii), __shfl(e45.y, ii));
      acc01 = pk_fma(up2(u0), w01, acc01);
      acc23 = pk_fma(up2(u1), w23, acc23);
      acc45 = pk_fma(up2(u2), w45, acc45);
    }
  } else {
    // ---- slow path (td > 64): single pass, no max pre-pass ----
    {
      const float4* sp = (const float4*)&sal[(long)d * SALS];
      float4 sA = sp[0], sB = sp[1];
      float2 al01 = pk_add(pk2(sA.x, sA.y), dal01);
      float2 al23 = pk_add(pk2(sA.z, sA.w), dal23);
      float2 al45 = pk_add(pk2(sB.x, sB.y), dal45);
      al01 = pk_fma(ns2, pk_min(al01, z2), pk_max(al01, z2));
      al23 = pk_fma(ns2, pk_min(al23, z2), pk_max(al23, z2));
      al45 = pk_fma(ns2, pk_min(al45, z2), pk_max(al45, z2));
      den01 = pk2(expf(al01.x - K01.x), expf(al01.y - K01.y));
      den23 = pk2(expf(al23.x - K23.x), expf(al23.y - K23.y));
      den45 = pk2(expf(al45.x - K45.x), expf(al45.y - K45.y));
    }
    acc01 = pk_mul(up2(ck0[0]), den01);
    acc23 = pk_mul(up2(ck1[0]), den23);
    acc45 = pk_mul(up2(ck2[0]), den45);
    for (int base = o0; base < o1; base += 64) {
      int cs = o1 - base; if (cs > 64) cs = 64;
      int j = base + lane;
      float2 e01 = z2, e23 = z2, e45 = z2;
      int s = 0;
      if (j < o1) {
        s = scsr[j];
        const float4* sp = (const float4*)&sal[(long)s * SALS];
        float4 sA = sp[0], sB = sp[1];
        float2 al01 = pk_add(pk2(sA.x, sA.y), dal01);
        float2 al23 = pk_add(pk2(sA.z, sA.w), dal23);
        float2 al45 = pk_add(pk2(sB.x, sB.y), dal45);
        al01 = pk_fma(ns2, pk_min(al01, z2), pk_max(al01, z2));
        al23 = pk_fma(ns2, pk_min(al23, z2), pk_max(al23, z2));
        al45 = pk_fma(ns2, pk_min(al45, z2), pk_max(al45, z2));
        e01 = pk2(expf(al01.x - K01.x), expf(al01.y - K01.y));
        e23 = pk2(expf(al23.x - K23.x), expf(al23.y - K23.y));
        e45 = pk2(expf(al45.x - K45.x), expf(al45.y - K45.y));
      }
      den01 = pk_add(den01, wsum64_f2(e01));
      den23 = pk_add(den23, wsum64_f2(e23));
      den45 = pk_add(den45, wsum64_f2(e45));
      for (int jj = 0; jj < cs; ++jj) {
        int sj = __shfl(s, jj);
        const unsigned* rp = &h2p[(long)sj * 192 + lane * 3];
        unsigned u0 = rp[0], u1 = rp[1], u2 = rp[2];
        float2 w01 = pk2(__shfl(e01.x, jj), __shfl(e01.y, jj));
        float2 w23 = pk2(__shfl(e23.x, jj), __shfl(e23.y, jj));
        float2 w45 = pk2(__shfl(e45.x, jj), __shfl(e45.y, jj));
        acc01 = pk_fma(up2(u0), w01, acc01);
        acc23 = pk_fma(up2(u1), w23, acc23);
        acc45 = pk_fma(up2(u2), w45, acc45);
      }
    }
  }

  float o = acc01.x / den01.x + acc01.y / den01.y +
            acc23.x / den23.x + acc23.y / den23.y +
            acc45.x / den45.x + acc45.y / den45.y;
  xm[(long)d * 64 + lane] = o * (1.0f / NH);
}

// fitness[d] = sigmoid(bsc[d] * (1 + sum_CSR dot(an[s], an[d])))
// 4 concurrent edges per wave: 16 lanes x uint2 per 128B row.
__global__ __launch_bounds__(256)
void k_cosout(const int* __restrict__ soff, const int* __restrict__ scsr,
              const unsigned* __restrict__ an32, const float* __restrict__ bsc,
              float* __restrict__ out, int n) {
  const int lane = threadIdx.x & 63;
  const int p = lane & 15;
  const int hf = lane >> 4;
  const int d = blockIdx.x * 4 + (threadIdx.x >> 6);
  if (d >= n) return;
  const int o0 = soff[d], o1 = soff[d + 1];
  uint2 ud = *(const uint2*)&an32[(long)d * 32 + 2 * p];
  float d0 = bflo(ud.x), d1 = bfhi(ud.x), d2 = bflo(ud.y), d3 = bfhi(ud.y);
  float cl = 0.f;
  for (int j = o0 + hf; j < o1; j += 4) {
    long s = scsr[j];
    uint2 u = *(const uint2*)&an32[s * 32 + 2 * p];
    cl += d0 * bflo(u.x) + d1 * bfhi(u.x) + d2 * bflo(u.y) + d3 * bfhi(u.y);
  }
  float cs = wave_sum64(cl) + 1.0f;   // self-cosine == 1 exactly
  if (lane == 0) out[d] = 1.0f / (1.0f + expf(-bsc[d] * cs));
}

// ---------- launcher ----------
static inline unsigned gsblocks(long total) {
  long b = (total + TPB - 1) / TPB;
  if (b > 131072) b = 131072;
  return (unsigned)b;
}

extern "C" void kernel_launch(void* const* d_in, const int* in_sizes, int n_in,
                              void* d_out, int out_size, void* d_ws, size_t ws_size,
                              hipStream_t stream) {
  const float* x   = (const float*)d_in[0];
  const float* Wg  = (const float*)d_in[1];
  const float* bg  = (const float*)d_in[2];
  const float* Wt  = (const float*)d_in[3];
  const float* att = (const float*)d_in[4];
  const float* W1  = (const float*)d_in[5];
  const float* W2  = (const float*)d_in[6];
  const float* b2  = (const float*)d_in[7];
  const int* src   = (const int*)d_in[8];
  const int* dst   = (const int*)d_in[9];

  const long n   = in_sizes[0] / 64;   // 50000
  const long en  = in_sizes[8];        // E + N
  const long E   = en - n;             // real edges (ei), loops excluded
  const int  nb  = (int)((n + 2047) / 2048);

  char* base = (char*)d_ws;
  size_t off = 0;
  auto alloc = [&](size_t bytes) -> void* {
    void* p = base + off;
    off += (bytes + 255) & ~(size_t)255;
    return p;
  };
  int*   gcnt = (int*)alloc(n * 4);
  int*   scnt = (int*)alloc(n * 4);   // contiguous with gcnt (one memset)
  int*   goff = (int*)alloc((n + 1) * 4);
  int*   soff = (int*)alloc((n + 1) * 4);
  int*   gcur = (int*)alloc(n * 4);
  int*   scur = (int*)alloc(n * 4);
  int*   gcsr = (int*)alloc(E * 4);
  int*   scsr = (int*)alloc(E * 4);
  int*   bsum = (int*)alloc(2 * (size_t)nb * 4);
  float* dinv = (float*)alloc(n * 4);
  unsigned* hs32 = (unsigned*)alloc(n * 32 * 4);      // bf16 pairs of (x@Wg)*dinv
  float* xpj  = (float*)alloc(n * 64 * 4);            // later anorm (bf16)
  float* xmb  = (float*)alloc(n * 64 * 4);            // xm buffer
  unsigned* h2p = (unsigned*)alloc(n * 192 * 4);      // channel-major bf16 pairs
  float* sal  = (float*)alloc(n * SALS * 4);
  float* bsc  = (float*)alloc(n * 4);
  unsigned short* anorm = (unsigned short*)xpj;       // alias (xpj dead after h2)
  float* out  = (float*)d_out;

  const unsigned rowblk  = (unsigned)((n + 63) / 64);
  const unsigned nodeblk = (unsigned)((n + 3) / 4);

  // ---- CSR build (E edges only; self-loops analytic) + dinv ----
  hipMemsetAsync(gcnt, 0, (size_t)((char*)scnt - (char*)gcnt) + n * 4, stream);
  k_cnt<<<gsblocks(E), TPB, 0, stream>>>(src, dst, gcnt, scnt, E);
  k_scanA<<<2 * nb, 1024, 0, stream>>>(gcnt, scnt, bsum, dinv, (int)n, nb);
  k_scanC<<<2 * nb, 1024, 0, stream>>>(gcnt, goff, gcur, scnt, soff, scur,
                                       bsum, (int)n, nb);
  k_scatter<<<gsblocks(E), TPB, 0, stream>>>(src, dst, gcur, gcsr, scur, scsr, E);

  // ---- hs = (x @ W_gcn) * dinv[row], bf16 ----
  { dim3 g(rowblk, 1);
    k_gemm64v3<1><<<g, 256, 0, stream>>>(x, Wg, nullptr, (unsigned short*)hs32,
                                         dinv, nullptr, nullptr, nullptr, (int)n, 64); }

  // ---- xpj = bg + dinv[d] * (2*hs[d] + sum_CSR hs[s]) ----
  k_gcnb<<<nodeblk, 256, 0, stream>>>(goff, gcsr, hs32, dinv, bg, xpj, (int)n);

  // ---- h2 = xpj @ weight (bf16 channel-major packed) + fused sal ----
  k_gemm_h2<<<rowblk, 256, 0, stream>>>(xpj, Wt, h2p, att, sal, (int)n);

  // ---- fused attention (self inline, no-max softmax, packed math) -> xm ----
  k_mega<<<nodeblk, 256, 0, stream>>>(soff, scsr, h2p, sal, att, xmb, (int)n);

  // ---- a = normalize(xm @ W1) (bf16, aliases xpj) + bsc ----
  { dim3 g(rowblk, 1);
    k_gemm64v3<2><<<g, 256, 0, stream>>>(xmb, W1, nullptr, anorm, nullptr,
                                         W2, b2, bsc, (int)n, 64); }

  // ---- cosine + sigmoid -> out (self-cos = 1 analytic) ----
  k_cosout<<<nodeblk, 256, 0, stream>>>(soff, scsr, (const unsigned*)anorm,
                                        bsc, out, (int)n);
}